// Round 2
// baseline (1713.812 us; speedup 1.0000x reference)
//
#include <hip/hip_runtime.h>
#include <math.h>

#define SEQ 577
#define NH 12
#define DH 64
#define EMB 768
#define NBATCH 16

// ---------------------------------------------------------------------------
// GEMM (NT): C[i,j] = sum_k A[i,k] * B[j,k].  A:[M,K] row-major, B:[N,K] row-major.
// mode 0: scatter-write into q/k/v workspace laid out (Bc,H,N,D)
// mode 1: plain row-major C0[M,N]
// ---------------------------------------------------------------------------
#define TILE 128
#define BKK 16

__global__ __launch_bounds__(256) void gemm_nt_kernel(
    const float* __restrict__ A, const float* __restrict__ Bm,
    float* __restrict__ C0, float* __restrict__ C1, float* __restrict__ C2,
    int M, int N, int K, int mode)
{
  __shared__ float As[BKK][TILE];
  __shared__ float Bs[BKK][TILE];
  const int tid = threadIdx.x;
  const int r0 = blockIdx.y * TILE;
  const int c0 = blockIdx.x * TILE;
  const int ty = tid >> 4, tx = tid & 15;
  const int lr = tid >> 2;   // 0..63: row within tile (two groups of 64)
  const int lq = tid & 3;    // k-quad

  float acc[8][8];
#pragma unroll
  for (int i = 0; i < 8; ++i)
#pragma unroll
    for (int j = 0; j < 8; ++j) acc[i][j] = 0.f;

  for (int k0 = 0; k0 < K; k0 += BKK) {
#pragma unroll
    for (int g = 0; g < 2; ++g) {
      int r = lr + g*64;
      int gr = r0 + r;
      float4 a = make_float4(0.f,0.f,0.f,0.f);
      if (gr < M) a = *(const float4*)&A[(size_t)gr*K + k0 + lq*4];
      As[lq*4+0][r] = a.x; As[lq*4+1][r] = a.y;
      As[lq*4+2][r] = a.z; As[lq*4+3][r] = a.w;
      int gc = c0 + r;
      float4 b = make_float4(0.f,0.f,0.f,0.f);
      if (gc < N) b = *(const float4*)&Bm[(size_t)gc*K + k0 + lq*4];
      Bs[lq*4+0][r] = b.x; Bs[lq*4+1][r] = b.y;
      Bs[lq*4+2][r] = b.z; Bs[lq*4+3][r] = b.w;
    }
    __syncthreads();
#pragma unroll
    for (int kk = 0; kk < BKK; ++kk) {
      float a[8], b[8];
      *(float4*)&a[0] = *(float4*)&As[kk][ty*8];
      *(float4*)&a[4] = *(float4*)&As[kk][ty*8+4];
      *(float4*)&b[0] = *(float4*)&Bs[kk][tx*8];
      *(float4*)&b[4] = *(float4*)&Bs[kk][tx*8+4];
#pragma unroll
      for (int i = 0; i < 8; ++i)
#pragma unroll
        for (int j = 0; j < 8; ++j)
          acc[i][j] = fmaf(a[i], b[j], acc[i][j]);
    }
    __syncthreads();
  }

#pragma unroll
  for (int i = 0; i < 8; ++i) {
    int gr = r0 + ty*8 + i;
    if (gr >= M) continue;
    int brow = gr / SEQ;
    int nrow = gr - brow*SEQ;
#pragma unroll
    for (int jq = 0; jq < 2; ++jq) {
      int col = c0 + tx*8 + jq*4;
      if (col >= N) continue;
      float4 v = make_float4(acc[i][jq*4+0], acc[i][jq*4+1],
                             acc[i][jq*4+2], acc[i][jq*4+3]);
      if (mode == 1) {
        *(float4*)&C0[(size_t)gr*N + col] = v;
      } else {
        int t  = col / EMB;
        int ct = col - t*EMB;
        int h  = ct >> 6;
        int dd = ct & 63;
        float* dst = (t == 0) ? C0 : (t == 1) ? C1 : C2;
        *(float4*)&dst[(((size_t)brow*NH + h)*SEQ + nrow)*DH + dd] = v;
      }
    }
  }
}

// ---------------------------------------------------------------------------
// Fused attention with relative-position bias on Q and V paths.
// One block = 16 query rows of one (b,h). 4 waves, 4 rows/wave.
// q_pos bias: per-row 50-bin dot tables. v_pos bias: 24-bin col/row prob sums.
// LDS: Ss 37376 + KV 17408 + PB 10496 = 65280 B (< 64 KiB limit).
// ---------------------------------------------------------------------------
#define TR 16
#define SW 584   // 576 + 8 pad; pad entries hold p=0 after softmax

__global__ __launch_bounds__(256) void attn_kernel(
    const float* __restrict__ qg, const float* __restrict__ kg,
    const float* __restrict__ vg,
    const float* __restrict__ qxe, const float* __restrict__ qye,
    const float* __restrict__ vxe, const float* __restrict__ vye,
    float* __restrict__ og)
{
  __shared__ float Ss[TR][SW];
  __shared__ float KV[64][68];
  __shared__ float PB[TR][164];

  const int tid  = threadIdx.x;
  const int wave = tid >> 6, lane = tid & 63;
  const int bh = blockIdx.y;            // 0 .. Bc*NH-1 (chunk-local)
  const int r0 = blockIdx.x * TR;
  const size_t base = (size_t)bh * SEQ * DH;

  // ---- Phase 0: stage Q rows; build qx_dot / qy_dot tables ----
  {
    int r = tid >> 4, qd = tid & 15;
    int n = r0 + r;
    float4 v = make_float4(0.f,0.f,0.f,0.f);
    if (n < SEQ) v = *(const float4*)&qg[base + (size_t)n*DH + qd*4];
    *(float4*)&PB[r][qd*4] = v;
  }
  __syncthreads();
  for (int task = tid; task < TR*50; task += 256) {
    int r = task / 50, bin = task - (task/50)*50;
    float sx = 0.f, sy = 0.f;
#pragma unroll
    for (int d = 0; d < 32; ++d) {
      sx = fmaf(PB[r][d],    qxe[bin*32 + d], sx);
      sy = fmaf(PB[r][32+d], qye[bin*32 + d], sy);
    }
    PB[r][64 + bin]  = sx;
    PB[r][114 + bin] = sy;
  }
  __syncthreads();

  // ---- Phase A: scores S = (Q.K^T + bias) * 0.125 ----
  for (int t = 0; t < 10; ++t) {
    int m0 = t*64;
    {
      int qq = tid & 15, j0 = tid >> 4;
#pragma unroll
      for (int ii = 0; ii < 4; ++ii) {
        int j = j0 + ii*16;
        int m = m0 + j;
        float4 v = make_float4(0.f,0.f,0.f,0.f);
        if (m < SEQ) v = *(const float4*)&kg[base + (size_t)m*DH + qq*4];
        *(float4*)&KV[j][qq*4] = v;
      }
    }
    __syncthreads();
    float4 k4[16];
#pragma unroll
    for (int c = 0; c < 16; ++c) k4[c] = *(float4*)&KV[lane][c*4];
    int m = m0 + lane;
    int xm = 0, ym = 0;
    if (m > 0) { xm = (m-1) % 24; ym = (m-1) / 24; }
#pragma unroll
    for (int rr = 0; rr < 4; ++rr) {
      int r = wave*4 + rr;
      int n = r0 + r;
      float s = 0.f;
#pragma unroll
      for (int c = 0; c < 16; ++c) {
        float4 q4 = *(float4*)&PB[r][c*4];
        s = fmaf(k4[c].x, q4.x, s); s = fmaf(k4[c].y, q4.y, s);
        s = fmaf(k4[c].z, q4.z, s); s = fmaf(k4[c].w, q4.w, s);
      }
      int xi = 0, yi = 0;
      if (m > 0 && n > 0) {            // cls row/col -> index 0
        int xn = (n-1) % 24, yn = (n-1) / 24;
        xi = xm - xn + 25; yi = ym - yn + 25;   // |diff|<=23: clip never fires
      }
      s = (s + PB[r][64 + xi] + PB[r][114 + yi]) * 0.125f;
      if (m0 + lane < SW) Ss[r][m0 + lane] = (m < SEQ) ? s : -INFINITY;
    }
    __syncthreads();
  }

  // ---- Phase B: softmax + colsum/rowsum (same-wave rows; no barrier needed) ----
#pragma unroll
  for (int rr = 0; rr < 4; ++rr) {
    int r = wave*4 + rr;
    float sv[10];
    float mx = -INFINITY;
#pragma unroll
    for (int k = 0; k < 9; ++k) { sv[k] = Ss[r][lane + k*64]; mx = fmaxf(mx, sv[k]); }
    {
      float v = Ss[r][576 + (lane & 7)];
      sv[9] = (lane < 8) ? v : -INFINITY;
      mx = fmaxf(mx, sv[9]);
    }
#pragma unroll
    for (int off = 32; off >= 1; off >>= 1) mx = fmaxf(mx, __shfl_xor(mx, off));
    float sum = 0.f;
#pragma unroll
    for (int k = 0; k < 9; ++k) {
      float p = __expf(sv[k] - mx);
      Ss[r][lane + k*64] = p;
      sum += p;
    }
    {
      float p = __expf(sv[9] - mx);
      if (lane < 8) Ss[r][576 + lane] = p;   // pad entries get exp(-inf)=0
      sum += (lane < 8) ? p : 0.f;
    }
#pragma unroll
    for (int off = 32; off >= 1; off >>= 1) sum += __shfl_xor(sum, off);
    if (lane == 0) PB[r][48] = sum;
    if (lane < 24) {                     // column-class sums (x path), m>=1
      float cs = 0.f;
#pragma unroll
      for (int g = 0; g < 24; ++g) cs += Ss[r][1 + g*24 + lane];
      PB[r][lane] = cs;
    } else if (lane >= 32 && lane < 56) { // row-class sums (y path), m>=1
      int rw = lane - 32;
      float rs = 0.f;
#pragma unroll
      for (int g = 0; g < 24; ++g) rs += Ss[r][1 + rw*24 + g];
      PB[r][24 + rw] = rs;
    }
  }

  // ---- Phase C: O = P.V ; lanes = (m%4, d-quad) ----
  const int ml = lane >> 4, qd = lane & 15;
  float4 oa[4];
#pragma unroll
  for (int rr = 0; rr < 4; ++rr) oa[rr] = make_float4(0.f,0.f,0.f,0.f);

  for (int t = 0; t < 10; ++t) {
    int m0 = t*64;
    __syncthreads();
    {
      int qq = tid & 15, j0 = tid >> 4;
#pragma unroll
      for (int ii = 0; ii < 4; ++ii) {
        int j = j0 + ii*16;
        int m = m0 + j;
        float4 v = make_float4(0.f,0.f,0.f,0.f);
        if (m < SEQ) v = *(const float4*)&vg[base + (size_t)m*DH + qq*4];
        *(float4*)&KV[j][qq*4] = v;
      }
    }
    __syncthreads();
#pragma unroll
    for (int mm = 0; mm < 16; ++mm) {
      int j = mm*4 + ml;
      float4 v4 = *(float4*)&KV[j][qd*4];
      int m = m0 + j;
      int mi = (m < SW) ? m : (SW-1);    // pad entries hold p=0
#pragma unroll
      for (int rr = 0; rr < 4; ++rr) {
        int r = wave*4 + rr;
        float p = Ss[r][mi];
        oa[rr].x = fmaf(p, v4.x, oa[rr].x);
        oa[rr].y = fmaf(p, v4.y, oa[rr].y);
        oa[rr].z = fmaf(p, v4.z, oa[rr].z);
        oa[rr].w = fmaf(p, v4.w, oa[rr].w);
      }
    }
  }

  // reduce the 4 m%4 partials
#pragma unroll
  for (int rr = 0; rr < 4; ++rr) {
    oa[rr].x += __shfl_xor(oa[rr].x, 16);
    oa[rr].y += __shfl_xor(oa[rr].y, 16);
    oa[rr].z += __shfl_xor(oa[rr].z, 16);
    oa[rr].w += __shfl_xor(oa[rr].w, 16);
    oa[rr].x += __shfl_xor(oa[rr].x, 32);
    oa[rr].y += __shfl_xor(oa[rr].y, 32);
    oa[rr].z += __shfl_xor(oa[rr].z, 32);
    oa[rr].w += __shfl_xor(oa[rr].w, 32);
  }

  if (ml == 0) {
    const float* tab = (qd < 8) ? vxe : vye;
    int d0 = qd * 4;
    int dd = d0 & 31;
    int bI = bh / NH, hI = bh - bI*NH;
#pragma unroll
    for (int rr = 0; rr < 4; ++rr) {
      int r = wave*4 + rr;
      int n = r0 + r;
      if (n >= SEQ) continue;
      float L  = PB[r][48];
      float p0 = Ss[r][0];
      float4 bias;
      if (n == 0) {                      // X_DIS[0,m]=0 for all m -> L * emb[0]
        bias.x = L * tab[dd+0]; bias.y = L * tab[dd+1];
        bias.z = L * tab[dd+2]; bias.w = L * tab[dd+3];
      } else {
        int xn = (n-1) % 24, yn = (n-1) / 24;
        int cn = (qd < 8) ? xn : yn;
        bias.x = p0 * tab[dd+0]; bias.y = p0 * tab[dd+1];
        bias.z = p0 * tab[dd+2]; bias.w = p0 * tab[dd+3];
#pragma unroll
        for (int c = 0; c < 24; ++c) {
          float w = PB[r][(qd < 8) ? c : (24 + c)];
          int idx = c - cn + 25;
          const float* tv = &tab[idx*32 + dd];
          bias.x = fmaf(w, tv[0], bias.x);
          bias.y = fmaf(w, tv[1], bias.y);
          bias.z = fmaf(w, tv[2], bias.z);
          bias.w = fmaf(w, tv[3], bias.w);
        }
      }
      float inv = 1.0f / L;
      float4 o;
      o.x = (oa[rr].x + bias.x) * inv;
      o.y = (oa[rr].y + bias.y) * inv;
      o.z = (oa[rr].z + bias.z) * inv;
      o.w = (oa[rr].w + bias.w) * inv;
      *(float4*)&og[(((size_t)bI*SEQ + n)*NH + hI)*DH + d0] = o;
    }
  }
}

// ---------------------------------------------------------------------------
// Batch-chunked driver: batches are independent end-to-end, so process
// Bc = 16/nc batches per chunk, reusing ONE ws region of 4 buffers sized
// Bc*NH*SEQ*DH floats each. nc chosen from ws_size (min 2 this round —
// deliberate bisection of the ws-overflow theory from round 1).
// Stream-ordered chunk serialization => no cross-chunk hazards.
// ---------------------------------------------------------------------------
extern "C" void kernel_launch(void* const* d_in, const int* in_sizes, int n_in,
                              void* d_out, int out_size, void* d_ws, size_t ws_size,
                              hipStream_t stream)
{
  const float* x     = (const float*)d_in[0];
  const float* qkvw  = (const float*)d_in[1];
  const float* projw = (const float*)d_in[2];
  const float* qxe   = (const float*)d_in[3];
  const float* qye   = (const float*)d_in[4];
  const float* vxe   = (const float*)d_in[5];
  const float* vye   = (const float*)d_in[6];
  float* out = (float*)d_out;

  const size_t SLB = (size_t)NBATCH * NH * SEQ * DH;  // 7,090,176 floats total/buffer

  int nc = 2;                                          // forced >=2 (see theory)
  while (nc < 16 && (16 * SLB / (size_t)nc) > ws_size) nc *= 2;

  const int Bc  = NBATCH / nc;
  const int Mc  = Bc * SEQ;
  const size_t SLc = SLB / nc;                         // floats per chunk buffer

  float* qws = (float*)d_ws;
  float* kws = qws + SLc;
  float* vws = kws + SLc;
  float* ows = vws + SLc;

  dim3 g1(3*EMB/TILE, (Mc + TILE - 1)/TILE);
  dim3 g2((SEQ + TR - 1)/TR, Bc * NH);
  dim3 g3(EMB/TILE, (Mc + TILE - 1)/TILE);

  for (int c = 0; c < nc; ++c) {
    const float* xc  = x   + (size_t)c * Mc * EMB;
    float*       oc  = out + (size_t)c * Mc * EMB;

    gemm_nt_kernel<<<g1, 256, 0, stream>>>(xc, qkvw, qws, kws, vws,
                                           Mc, 3*EMB, EMB, 0);
    attn_kernel<<<g2, 256, 0, stream>>>(qws, kws, vws, qxe, qye, vxe, vye, ows);
    gemm_nt_kernel<<<g3, 256, 0, stream>>>(ows, projw, oc, nullptr, nullptr,
                                           Mc, EMB, EMB, 1);
  }
}

// Round 3
// 1193.187 us; speedup vs baseline: 1.4363x; 1.4363x over previous
//
#include <hip/hip_runtime.h>
#include <math.h>

#define SEQ 577
#define NH 12
#define DH 64
#define EMB 768
#define NBATCH 16
#define NC 2
#define BC (NBATCH/NC)
#define MC (BC*SEQ)      // 4616 rows per chunk
#define BHC (BC*NH)      // 96 (b,h) per chunk

typedef float f32x4 __attribute__((ext_vector_type(4)));
typedef short s16x8 __attribute__((ext_vector_type(8)));

__device__ __forceinline__ float bf2f(unsigned short u) {
  union { unsigned int i; float f; } c; c.i = ((unsigned int)u) << 16; return c.f;
}
__device__ __forceinline__ unsigned short f2bf(float f) {
  union { float f; unsigned int i; } c; c.f = f;
  unsigned int r = c.i + 0x7FFFu + ((c.i >> 16) & 1u);   // round-nearest-even
  return (unsigned short)(r >> 16);
}

// ---------------------------------------------------------------------------
__global__ __launch_bounds__(256) void cast_kernel(
    const float* __restrict__ s, unsigned short* __restrict__ d, int n4)
{
  int i = blockIdx.x * 256 + threadIdx.x;
  if (i < n4) {
    float4 v = *(const float4*)&s[(size_t)i*4];
    ushort4 o; o.x = f2bf(v.x); o.y = f2bf(v.y); o.z = f2bf(v.z); o.w = f2bf(v.w);
    *(ushort4*)&d[(size_t)i*4] = o;
  }
}

// ---------------------------------------------------------------------------
// bf16 MFMA GEMM (NT): C[i,j] = sum_k A[i,k]*B[j,k], K = 768 fixed.
// 128x128 tile, 4 waves, each wave 64x64 = 4x4 frags of 16x16x32.
// mode 0: scatter bf16 into q/k/v (Bc,H,N,D). mode 1: fp32 row-major Cf.
// A-frag: row=lane&15, k=(lane>>4)*8+j. D: col=lane&15, row=(lane>>4)*4+reg.
// LDS rows padded to 40 ushorts (80 B) -> 16B-aligned b128, ~2-way banks.
// ---------------------------------------------------------------------------
#define GT 128
__global__ __launch_bounds__(256) void gemm_bf16(
    const unsigned short* __restrict__ A, const unsigned short* __restrict__ Bm,
    unsigned short* __restrict__ Cq, unsigned short* __restrict__ Ck,
    unsigned short* __restrict__ Cv, float* __restrict__ Cf,
    int M, int N, int mode)
{
  __shared__ __align__(16) unsigned short As[GT][40];
  __shared__ __align__(16) unsigned short Bs[GT][40];
  const int tid = threadIdx.x;
  const int wave = tid >> 6, lane = tid & 63;
  const int wr = wave >> 1, wc = wave & 1;
  const int li = lane & 15, g = lane >> 4;
  const int r0 = blockIdx.y * GT, c0 = blockIdx.x * GT;
  const int srow = tid >> 1, sseg = tid & 1;

  f32x4 acc[4][4];
#pragma unroll
  for (int i = 0; i < 4; ++i)
#pragma unroll
    for (int j = 0; j < 4; ++j) { acc[i][j][0]=0.f; acc[i][j][1]=0.f; acc[i][j][2]=0.f; acc[i][j][3]=0.f; }

  for (int k0 = 0; k0 < EMB; k0 += 32) {
    uint4 a0 = {0,0,0,0}, a1 = {0,0,0,0}, b0 = {0,0,0,0}, b1 = {0,0,0,0};
    int gr = r0 + srow;
    if (gr < M) {
      const uint4* p = (const uint4*)&A[(size_t)gr*EMB + k0 + sseg*16];
      a0 = p[0]; a1 = p[1];
    }
    int gc = c0 + srow;
    if (gc < N) {
      const uint4* p = (const uint4*)&Bm[(size_t)gc*EMB + k0 + sseg*16];
      b0 = p[0]; b1 = p[1];
    }
    *(uint4*)&As[srow][sseg*16]   = a0;
    *(uint4*)&As[srow][sseg*16+8] = a1;
    *(uint4*)&Bs[srow][sseg*16]   = b0;
    *(uint4*)&Bs[srow][sseg*16+8] = b1;
    __syncthreads();

    s16x8 af[4], bfv[4];
#pragma unroll
    for (int i = 0; i < 4; ++i) af[i]  = *(const s16x8*)&As[wr*64 + i*16 + li][g*8];
#pragma unroll
    for (int j = 0; j < 4; ++j) bfv[j] = *(const s16x8*)&Bs[wc*64 + j*16 + li][g*8];
#pragma unroll
    for (int i = 0; i < 4; ++i)
#pragma unroll
      for (int j = 0; j < 4; ++j)
        acc[i][j] = __builtin_amdgcn_mfma_f32_16x16x32_bf16(af[i], bfv[j], acc[i][j], 0, 0, 0);
    __syncthreads();
  }

#pragma unroll
  for (int i = 0; i < 4; ++i) {
    int rbase = r0 + wr*64 + i*16 + g*4;
#pragma unroll
    for (int j = 0; j < 4; ++j) {
      int col = c0 + wc*64 + j*16 + li;
#pragma unroll
      for (int rg = 0; rg < 4; ++rg) {
        int gr = rbase + rg;
        if (gr >= M) continue;
        float val = acc[i][j][rg];
        if (mode == 1) {
          Cf[(size_t)gr*N + col] = val;
        } else {
          int t  = col / EMB;
          int ct = col - t*EMB;
          int h  = ct >> 6, dd = ct & 63;
          int brow = gr / SEQ, nrow = gr - brow*SEQ;
          unsigned short* dst = (t == 0) ? Cq : (t == 1) ? Ck : Cv;
          dst[(((size_t)brow*NH + h)*SEQ + nrow)*DH + dd] = f2bf(val);
        }
      }
    }
  }
}

// ---------------------------------------------------------------------------
// Fused attention, bf16 I/O. One block = 16 q-rows of one (b,h); 4 waves.
// Scores live in registers sc[4][10]; probs stored bf16 in Ps.
// KV[64][64] XOR-swizzled (phys quad = logical quad ^ (row&15)) -> min-phase LDS.
// LDS: Ps 18688 + KV 16384 + PB 10496 = 45568 B -> 3 blocks/CU.
// ---------------------------------------------------------------------------
#define TR 16
#define SW 584   // 577 cols + pad to 584; pad probs are 0

__global__ __launch_bounds__(256) void attn_kernel(
    const unsigned short* __restrict__ qg, const unsigned short* __restrict__ kg,
    const unsigned short* __restrict__ vg,
    const float* __restrict__ qxe, const float* __restrict__ qye,
    const float* __restrict__ vxe, const float* __restrict__ vye,
    unsigned short* __restrict__ og)
{
  __shared__ unsigned short Ps[TR][SW];
  __shared__ __align__(16) float KV[64][64];
  __shared__ __align__(16) float PB[TR][164];

  const int tid  = threadIdx.x;
  const int wave = tid >> 6, lane = tid & 63;
  const int li = lane & 15;
  const int bh = blockIdx.y;
  const int r0 = blockIdx.x * TR;
  const size_t base = (size_t)bh * SEQ * DH;

  // ---- Phase 0: stage Q (bf16->f32); build 50-bin qx/qy dot tables ----
  {
    int r = tid >> 4, qd = tid & 15;
    int n = r0 + r;
    float4 f = {0.f,0.f,0.f,0.f};
    if (n < SEQ) {
      ushort4 u = *(const ushort4*)&qg[base + (size_t)n*DH + qd*4];
      f.x = bf2f(u.x); f.y = bf2f(u.y); f.z = bf2f(u.z); f.w = bf2f(u.w);
    }
    *(float4*)&PB[r][qd*4] = f;
  }
  __syncthreads();
  for (int task = tid; task < TR*50; task += 256) {
    int r = task / 50, bin = task - (task/50)*50;
    float sx = 0.f, sy = 0.f;
#pragma unroll
    for (int d = 0; d < 32; ++d) {
      sx = fmaf(PB[r][d],    qxe[bin*32 + d], sx);
      sy = fmaf(PB[r][32+d], qye[bin*32 + d], sy);
    }
    PB[r][64 + bin]  = sx;
    PB[r][114 + bin] = sy;
  }
  __syncthreads();

  // ---- Phase A: scores in registers ----
  float sc[4][10];
  for (int t = 0; t < 10; ++t) {
    int m0 = t*64;
    {
      int qq = tid & 15, j0 = tid >> 4;
#pragma unroll
      for (int ii = 0; ii < 4; ++ii) {
        int j = j0 + ii*16;
        int m = m0 + j;
        float4 f = {0.f,0.f,0.f,0.f};
        if (m < SEQ) {
          ushort4 u = *(const ushort4*)&kg[base + (size_t)m*DH + qq*4];
          f.x = bf2f(u.x); f.y = bf2f(u.y); f.z = bf2f(u.z); f.w = bf2f(u.w);
        }
        *(float4*)&KV[j][(qq ^ (j & 15))*4] = f;
      }
    }
    __syncthreads();

    int m = m0 + lane;
    int xm = 0, ym = 0;
    if (m > 0) { xm = (m-1) % 24; ym = (m-1) / 24; }
    float sa[4], sb[4];
#pragma unroll
    for (int rr = 0; rr < 4; ++rr) { sa[rr] = 0.f; sb[rr] = 0.f; }
#pragma unroll
    for (int c4 = 0; c4 < 4; ++c4) {
      float4 kq[4];
#pragma unroll
      for (int cc = 0; cc < 4; ++cc)
        kq[cc] = *(const float4*)&KV[lane][(((c4*4+cc) ^ li)*4)];
#pragma unroll
      for (int rr = 0; rr < 4; ++rr) {
        int r = wave*4 + rr;
        float4 q0 = *(const float4*)&PB[r][(c4*4+0)*4];
        float4 q1 = *(const float4*)&PB[r][(c4*4+1)*4];
        float4 q2 = *(const float4*)&PB[r][(c4*4+2)*4];
        float4 q3 = *(const float4*)&PB[r][(c4*4+3)*4];
        sa[rr] = fmaf(kq[0].x,q0.x, fmaf(kq[0].y,q0.y, fmaf(kq[0].z,q0.z, fmaf(kq[0].w,q0.w, sa[rr]))));
        sb[rr] = fmaf(kq[1].x,q1.x, fmaf(kq[1].y,q1.y, fmaf(kq[1].z,q1.z, fmaf(kq[1].w,q1.w, sb[rr]))));
        sa[rr] = fmaf(kq[2].x,q2.x, fmaf(kq[2].y,q2.y, fmaf(kq[2].z,q2.z, fmaf(kq[2].w,q2.w, sa[rr]))));
        sb[rr] = fmaf(kq[3].x,q3.x, fmaf(kq[3].y,q3.y, fmaf(kq[3].z,q3.z, fmaf(kq[3].w,q3.w, sb[rr]))));
      }
    }
#pragma unroll
    for (int rr = 0; rr < 4; ++rr) {
      int r = wave*4 + rr, n = r0 + r;
      float s = sa[rr] + sb[rr];
      int xi = 0, yi = 0;
      if (m > 0 && n > 0 && n < SEQ) {
        int xn = (n-1) % 24, yn = (n-1) / 24;
        xi = xm - xn + 25; yi = ym - yn + 25;   // |diff|<=23: clip never fires
      }
      s = (s + PB[r][64 + xi] + PB[r][114 + yi]) * 0.125f;
      sc[rr][t] = (m < SEQ) ? s : -INFINITY;
    }
    __syncthreads();
  }

  // ---- Phase B: softmax from registers; probs -> Ps (bf16); col/row sums ----
#pragma unroll
  for (int rr = 0; rr < 4; ++rr) {
    int r = wave*4 + rr;
    float mx = -INFINITY;
#pragma unroll
    for (int t = 0; t < 10; ++t) mx = fmaxf(mx, sc[rr][t]);
#pragma unroll
    for (int off = 32; off >= 1; off >>= 1) mx = fmaxf(mx, __shfl_xor(mx, off));
    float sum = 0.f;
#pragma unroll
    for (int t = 0; t < 10; ++t) {
      float p = __expf(sc[rr][t] - mx);
      sum += p;
      int col = t*64 + lane;
      if (col < SW) Ps[r][col] = f2bf(p);   // pad cols 577..583 get exp(-inf)=0
    }
#pragma unroll
    for (int off = 32; off >= 1; off >>= 1) sum += __shfl_xor(sum, off);
    if (lane == 0) PB[r][48] = sum;
    if (lane < 24) {                     // x-path column-class sums, m>=1
      float cs = 0.f;
#pragma unroll
      for (int g2 = 0; g2 < 24; ++g2) cs += bf2f(Ps[r][1 + g2*24 + lane]);
      PB[r][lane] = cs;
    } else if (lane >= 32 && lane < 56) { // y-path row-class sums, m>=1
      int rw = lane - 32;
      float rs = 0.f;
#pragma unroll
      for (int g2 = 0; g2 < 24; ++g2) rs += bf2f(Ps[r][1 + rw*24 + g2]);
      PB[r][24 + rw] = rs;
    }
  }

  // ---- Phase C: O = P.V ; lanes = (m%4 group, d-quad); probs via shuffle ----
  const int ml = lane >> 4, qd = lane & 15;
  float4 oa[4];
#pragma unroll
  for (int rr = 0; rr < 4; ++rr) { oa[rr].x=0.f; oa[rr].y=0.f; oa[rr].z=0.f; oa[rr].w=0.f; }

  for (int t = 0; t < 10; ++t) {
    int m0 = t*64;
    __syncthreads();
    {
      int qq = tid & 15, j0 = tid >> 4;
#pragma unroll
      for (int ii = 0; ii < 4; ++ii) {
        int j = j0 + ii*16;
        int m = m0 + j;
        float4 f = {0.f,0.f,0.f,0.f};
        if (m < SEQ) {
          ushort4 u = *(const ushort4*)&vg[base + (size_t)m*DH + qq*4];
          f.x = bf2f(u.x); f.y = bf2f(u.y); f.z = bf2f(u.z); f.w = bf2f(u.w);
        }
        *(float4*)&KV[j][(qq ^ (j & 15))*4] = f;
      }
    }
    __syncthreads();

    float preg[4];
#pragma unroll
    for (int rr = 0; rr < 4; ++rr) {
      int mi = m0 + lane; if (mi > 583) mi = 583;
      preg[rr] = bf2f(Ps[wave*4 + rr][mi]);
    }
#pragma unroll
    for (int mm = 0; mm < 16; ++mm) {
      int j = mm*4 + ml;
      float4 v4 = *(const float4*)&KV[j][((qd ^ (j & 15))*4)];
#pragma unroll
      for (int rr = 0; rr < 4; ++rr) {
        float p = __shfl(preg[rr], j, 64);
        oa[rr].x = fmaf(p, v4.x, oa[rr].x);
        oa[rr].y = fmaf(p, v4.y, oa[rr].y);
        oa[rr].z = fmaf(p, v4.z, oa[rr].z);
        oa[rr].w = fmaf(p, v4.w, oa[rr].w);
      }
    }
  }

#pragma unroll
  for (int rr = 0; rr < 4; ++rr) {
    oa[rr].x += __shfl_xor(oa[rr].x, 16);
    oa[rr].y += __shfl_xor(oa[rr].y, 16);
    oa[rr].z += __shfl_xor(oa[rr].z, 16);
    oa[rr].w += __shfl_xor(oa[rr].w, 16);
    oa[rr].x += __shfl_xor(oa[rr].x, 32);
    oa[rr].y += __shfl_xor(oa[rr].y, 32);
    oa[rr].z += __shfl_xor(oa[rr].z, 32);
    oa[rr].w += __shfl_xor(oa[rr].w, 32);
  }

  if (ml == 0) {
    const float* tab = (qd < 8) ? vxe : vye;
    int d0 = qd * 4;
    int dd = d0 & 31;
    int bI = bh / NH, hI = bh - bI*NH;
#pragma unroll
    for (int rr = 0; rr < 4; ++rr) {
      int r = wave*4 + rr;
      int n = r0 + r;
      if (n >= SEQ) continue;
      float L  = PB[r][48];
      float p0 = bf2f(Ps[r][0]);
      float4 bias;
      if (n == 0) {                      // X_DIS[0,m]=0 for all m -> L * emb[0]
        bias.x = L * tab[dd+0]; bias.y = L * tab[dd+1];
        bias.z = L * tab[dd+2]; bias.w = L * tab[dd+3];
      } else {
        int xn = (n-1) % 24, yn = (n-1) / 24;
        int cn = (qd < 8) ? xn : yn;
        bias.x = p0 * tab[dd+0]; bias.y = p0 * tab[dd+1];
        bias.z = p0 * tab[dd+2]; bias.w = p0 * tab[dd+3];
#pragma unroll
        for (int c = 0; c < 24; ++c) {
          float w = PB[r][(qd < 8) ? c : (24 + c)];
          int idx = c - cn + 25;
          const float* tv = &tab[idx*32 + dd];
          bias.x = fmaf(w, tv[0], bias.x);
          bias.y = fmaf(w, tv[1], bias.y);
          bias.z = fmaf(w, tv[2], bias.z);
          bias.w = fmaf(w, tv[3], bias.w);
        }
      }
      float inv = 1.0f / L;
      ushort4 o;
      o.x = f2bf((oa[rr].x + bias.x) * inv);
      o.y = f2bf((oa[rr].y + bias.y) * inv);
      o.z = f2bf((oa[rr].z + bias.z) * inv);
      o.w = f2bf((oa[rr].w + bias.w) * inv);
      *(ushort4*)&og[(((size_t)bI*SEQ + n)*NH + hI)*DH + d0] = o;
    }
  }
}

// ---------------------------------------------------------------------------
// ws layout (ushorts): q,k,v,ows,xbf each 3,545,088 + wqkv 1,769,472 +
// wproj 589,824 = 20.08 M ushorts = 40.2 MB  (< 56.7 MB proven budget).
// ---------------------------------------------------------------------------
extern "C" void kernel_launch(void* const* d_in, const int* in_sizes, int n_in,
                              void* d_out, int out_size, void* d_ws, size_t ws_size,
                              hipStream_t stream)
{
  const float* x     = (const float*)d_in[0];
  const float* qkvw  = (const float*)d_in[1];
  const float* projw = (const float*)d_in[2];
  const float* qxe   = (const float*)d_in[3];
  const float* qye   = (const float*)d_in[4];
  const float* vxe   = (const float*)d_in[5];
  const float* vye   = (const float*)d_in[6];
  float* out = (float*)d_out;

  const size_t SLc = (size_t)BHC * SEQ * DH;   // 3,545,088 == MC*EMB
  unsigned short* qws   = (unsigned short*)d_ws;
  unsigned short* kws   = qws + SLc;
  unsigned short* vws   = kws + SLc;
  unsigned short* ows   = vws + SLc;
  unsigned short* xbf   = ows + SLc;
  unsigned short* wqkv  = xbf + SLc;
  unsigned short* wproj = wqkv + (size_t)3*EMB*EMB;

  cast_kernel<<<(3*EMB*EMB/4 + 255)/256, 256, 0, stream>>>(qkvw, wqkv, 3*EMB*EMB/4);
  cast_kernel<<<(EMB*EMB/4 + 255)/256, 256, 0, stream>>>(projw, wproj, EMB*EMB/4);

  dim3 g1(3*EMB/GT, (MC + GT - 1)/GT);   // 18 x 37
  dim3 g2((SEQ + TR - 1)/TR, BHC);       // 37 x 96
  dim3 g3(EMB/GT, (MC + GT - 1)/GT);     // 6 x 37

  for (int c = 0; c < NC; ++c) {
    const float* xc = x   + (size_t)c * MC * EMB;
    float*       oc = out + (size_t)c * MC * EMB;
    cast_kernel<<<(MC*EMB/4 + 255)/256, 256, 0, stream>>>(xc, xbf, MC*EMB/4);
    gemm_bf16<<<g1, 256, 0, stream>>>(xbf, wqkv, qws, kws, vws, nullptr, MC, 3*EMB, 0);
    attn_kernel<<<g2, 256, 0, stream>>>(qws, kws, vws, qxe, qye, vxe, vye, ows);
    gemm_bf16<<<g3, 256, 0, stream>>>(ows, wproj, nullptr, nullptr, nullptr, oc, MC, EMB, 1);
  }
}

// Round 4
// 618.668 us; speedup vs baseline: 2.7702x; 1.9286x over previous
//
#include <hip/hip_runtime.h>
#include <math.h>

#define SEQ 577
#define NH 12
#define DH 64
#define EMB 768
#define NBATCH 16
#define NC 2
#define BC (NBATCH/NC)
#define MC (BC*SEQ)      // 4616 rows per chunk
#define BHC (BC*NH)      // 96 (b,h) per chunk
#define VTS 592          // vt row stride in m (16 ushort aligned, >= 577)

typedef float f32x4 __attribute__((ext_vector_type(4)));
typedef short s16x8 __attribute__((ext_vector_type(8)));

__device__ __forceinline__ float bf2f(unsigned short u) {
  union { unsigned int i; float f; } c; c.i = ((unsigned int)u) << 16; return c.f;
}
__device__ __forceinline__ unsigned short f2bf(float f) {
  union { float f; unsigned int i; } c; c.f = f;
  unsigned int r = c.i + 0x7FFFu + ((c.i >> 16) & 1u);   // round-nearest-even
  return (unsigned short)(r >> 16);
}

// ---------------------------------------------------------------------------
__global__ __launch_bounds__(256) void cast_kernel(
    const float* __restrict__ s, unsigned short* __restrict__ d, int n4)
{
  int i = blockIdx.x * 256 + threadIdx.x;
  if (i < n4) {
    float4 v = *(const float4*)&s[(size_t)i*4];
    ushort4 o; o.x = f2bf(v.x); o.y = f2bf(v.y); o.z = f2bf(v.z); o.w = f2bf(v.w);
    *(ushort4*)&d[(size_t)i*4] = o;
  }
}

// ---------------------------------------------------------------------------
// bf16 MFMA GEMM (NT). mode 0: scatter into q/k (b,h,n,d) and V TRANSPOSED
// vt (b,h,d,m) with m-stride VTS. mode 1: fp32 row-major Cf.
// ---------------------------------------------------------------------------
#define GT 128
__global__ __launch_bounds__(256) void gemm_bf16(
    const unsigned short* __restrict__ A, const unsigned short* __restrict__ Bm,
    unsigned short* __restrict__ Cq, unsigned short* __restrict__ Ck,
    unsigned short* __restrict__ Cv, float* __restrict__ Cf,
    int M, int N, int mode)
{
  __shared__ __align__(16) unsigned short As[GT][40];
  __shared__ __align__(16) unsigned short Bs[GT][40];
  const int tid = threadIdx.x;
  const int wave = tid >> 6, lane = tid & 63;
  const int wr = wave >> 1, wc = wave & 1;
  const int li = lane & 15, g = lane >> 4;
  const int r0 = blockIdx.y * GT, c0 = blockIdx.x * GT;
  const int srow = tid >> 1, sseg = tid & 1;

  f32x4 acc[4][4];
#pragma unroll
  for (int i = 0; i < 4; ++i)
#pragma unroll
    for (int j = 0; j < 4; ++j) { acc[i][j][0]=0.f; acc[i][j][1]=0.f; acc[i][j][2]=0.f; acc[i][j][3]=0.f; }

  for (int k0 = 0; k0 < EMB; k0 += 32) {
    uint4 a0 = {0,0,0,0}, a1 = {0,0,0,0}, b0 = {0,0,0,0}, b1 = {0,0,0,0};
    int gr = r0 + srow;
    if (gr < M) {
      const uint4* p = (const uint4*)&A[(size_t)gr*EMB + k0 + sseg*16];
      a0 = p[0]; a1 = p[1];
    }
    int gc = c0 + srow;
    if (gc < N) {
      const uint4* p = (const uint4*)&Bm[(size_t)gc*EMB + k0 + sseg*16];
      b0 = p[0]; b1 = p[1];
    }
    *(uint4*)&As[srow][sseg*16]   = a0;
    *(uint4*)&As[srow][sseg*16+8] = a1;
    *(uint4*)&Bs[srow][sseg*16]   = b0;
    *(uint4*)&Bs[srow][sseg*16+8] = b1;
    __syncthreads();

    s16x8 af[4], bfv[4];
#pragma unroll
    for (int i = 0; i < 4; ++i) af[i]  = *(const s16x8*)&As[wr*64 + i*16 + li][g*8];
#pragma unroll
    for (int j = 0; j < 4; ++j) bfv[j] = *(const s16x8*)&Bs[wc*64 + j*16 + li][g*8];
#pragma unroll
    for (int i = 0; i < 4; ++i)
#pragma unroll
      for (int j = 0; j < 4; ++j)
        acc[i][j] = __builtin_amdgcn_mfma_f32_16x16x32_bf16(af[i], bfv[j], acc[i][j], 0, 0, 0);
    __syncthreads();
  }

#pragma unroll
  for (int i = 0; i < 4; ++i) {
    int rbase = r0 + wr*64 + i*16 + g*4;
#pragma unroll
    for (int j = 0; j < 4; ++j) {
      int col = c0 + wc*64 + j*16 + li;
#pragma unroll
      for (int rg = 0; rg < 4; ++rg) {
        int gr = rbase + rg;
        if (gr >= M) continue;
        float val = acc[i][j][rg];
        if (mode == 1) {
          Cf[(size_t)gr*N + col] = val;
        } else {
          int t  = col / EMB;
          int ct = col - t*EMB;
          int h  = ct >> 6, dd = ct & 63;
          int brow = gr / SEQ, nrow = gr - brow*SEQ;
          if (t == 0)
            Cq[(((size_t)brow*NH + h)*SEQ + nrow)*DH + dd] = f2bf(val);
          else if (t == 1)
            Ck[(((size_t)brow*NH + h)*SEQ + nrow)*DH + dd] = f2bf(val);
          else
            Cv[(((size_t)brow*NH + h)*DH + dd)*VTS + nrow] = f2bf(val);
        }
      }
    }
  }
}

// ---------------------------------------------------------------------------
// MFMA fused attention. Block = 32 q-rows of one (b,h); 4 waves.
// QK^T + q-bias -> 80 score regs -> softmax -> Ps bf16 -> PV (V pre-transposed).
// LDS: Ps 37376 + KV 9216 + TBCS 6400 + red 512 = 53504 B -> 3 blocks/CU.
// TBCS region: Phase A = qx/qy bf16 tables [32][100]; Phase B/C = fp32
// colsum[24]+rowsum[24]+L per row ([32][49]).
// ---------------------------------------------------------------------------
#define TRB 32
#define SW 584   // Ps m-stride: 16B-aligned, 2-way (free) LDS phase

__global__ __launch_bounds__(256, 3) void attn_kernel(
    const unsigned short* __restrict__ qg, const unsigned short* __restrict__ kg,
    const unsigned short* __restrict__ vtg,
    const float* __restrict__ qxe, const float* __restrict__ qye,
    const float* __restrict__ vxe, const float* __restrict__ vye,
    unsigned short* __restrict__ og)
{
  __shared__ __align__(16) unsigned short Ps[TRB][SW];
  __shared__ __align__(16) unsigned short KV[64][72];
  __shared__ __align__(16) unsigned char  TBCS[TRB*200];
  __shared__ __align__(16) float red[TRB][4];

  const int tid  = threadIdx.x;
  const int wave = tid >> 6, lane = tid & 63;
  const int li = lane & 15, g = lane >> 4;
  const int bh = blockIdx.y;
  const int r0 = blockIdx.x * TRB;
  const size_t qkbase = (size_t)bh * SEQ * DH;
  const size_t vtbase = (size_t)bh * DH * VTS;
  const s16x8 z8 = {0,0,0,0,0,0,0,0};

  // ---- Q A-frags from global (kept resident) ----
  s16x8 qf[2][2];
#pragma unroll
  for (int i = 0; i < 2; ++i) {
    int n = r0 + i*16 + li;
#pragma unroll
    for (int s = 0; s < 2; ++s)
      qf[i][s] = (n < SEQ) ? *(const s16x8*)&qg[qkbase + (size_t)n*DH + s*32 + g*8] : z8;
  }

  // ---- bias dot tables via MFMA: qx_dot/qy_dot [32 rows][50 bins] bf16 ----
  unsigned short* TB = (unsigned short*)TBCS;          // row stride 100
  {
    int bin = wave*16 + li;
    s16x8 bx = z8, by = z8;
    if (bin < 50) {
      float4 x0 = *(const float4*)&qxe[bin*32 + g*8];
      float4 x1 = *(const float4*)&qxe[bin*32 + g*8 + 4];
      float4 y0 = *(const float4*)&qye[bin*32 + g*8];
      float4 y1 = *(const float4*)&qye[bin*32 + g*8 + 4];
      bx[0]=f2bf(x0.x); bx[1]=f2bf(x0.y); bx[2]=f2bf(x0.z); bx[3]=f2bf(x0.w);
      bx[4]=f2bf(x1.x); bx[5]=f2bf(x1.y); bx[6]=f2bf(x1.z); bx[7]=f2bf(x1.w);
      by[0]=f2bf(y0.x); by[1]=f2bf(y0.y); by[2]=f2bf(y0.z); by[3]=f2bf(y0.w);
      by[4]=f2bf(y1.x); by[5]=f2bf(y1.y); by[6]=f2bf(y1.z); by[7]=f2bf(y1.w);
    }
    f32x4 ax0={0.f,0.f,0.f,0.f}, ax1={0.f,0.f,0.f,0.f};
    f32x4 ay0={0.f,0.f,0.f,0.f}, ay1={0.f,0.f,0.f,0.f};
    ax0 = __builtin_amdgcn_mfma_f32_16x16x32_bf16(qf[0][0], bx, ax0, 0,0,0);
    ax1 = __builtin_amdgcn_mfma_f32_16x16x32_bf16(qf[1][0], bx, ax1, 0,0,0);
    ay0 = __builtin_amdgcn_mfma_f32_16x16x32_bf16(qf[0][1], by, ay0, 0,0,0);
    ay1 = __builtin_amdgcn_mfma_f32_16x16x32_bf16(qf[1][1], by, ay1, 0,0,0);
    if (bin < 50) {
#pragma unroll
      for (int rg = 0; rg < 4; ++rg) {
        TB[(g*4+rg)*100      + bin] = f2bf(ax0[rg]);
        TB[(16+g*4+rg)*100   + bin] = f2bf(ax1[rg]);
        TB[(g*4+rg)*100 + 50 + bin] = f2bf(ay0[rg]);
        TB[(16+g*4+rg)*100+50+ bin] = f2bf(ay1[rg]);
      }
    }
  }

  // row coords for bias (per i,rg)
  int xn[2][4], yn[2][4];
#pragma unroll
  for (int i = 0; i < 2; ++i)
#pragma unroll
    for (int rg = 0; rg < 4; ++rg) {
      int n = r0 + i*16 + g*4 + rg;
      if (n > 0 && n <= SEQ) { xn[i][rg] = (n-1) % 24; yn[i][rg] = (n-1) / 24; }
      else { xn[i][rg] = 0; yn[i][rg] = 0; }
    }
  __syncthreads();   // tables visible

  // ---- Phase A: QK^T + bias, scores -> regs ----
  float sreg[2][10][4];
#pragma unroll
  for (int kt = 0; kt < 10; ++kt) {
    int m0 = kt*64;
    {  // stage K tile (64 m x 64 d)
      int mm = m0 + (tid >> 2), seg = tid & 3;
      uint4 v0 = {0,0,0,0}, v1 = {0,0,0,0};
      if (mm < SEQ) {
        const uint4* p = (const uint4*)&kg[qkbase + (size_t)mm*DH + seg*16];
        v0 = p[0]; v1 = p[1];
      }
      *(uint4*)&KV[tid >> 2][seg*16]     = v0;
      *(uint4*)&KV[tid >> 2][seg*16 + 8] = v1;
    }
    __syncthreads();
    s16x8 kf0 = *(const s16x8*)&KV[wave*16 + li][g*8];
    s16x8 kf1 = *(const s16x8*)&KV[wave*16 + li][32 + g*8];
    f32x4 a0 = {0.f,0.f,0.f,0.f}, a1 = {0.f,0.f,0.f,0.f};
    a0 = __builtin_amdgcn_mfma_f32_16x16x32_bf16(qf[0][0], kf0, a0, 0,0,0);
    a1 = __builtin_amdgcn_mfma_f32_16x16x32_bf16(qf[1][0], kf0, a1, 0,0,0);
    a0 = __builtin_amdgcn_mfma_f32_16x16x32_bf16(qf[0][1], kf1, a0, 0,0,0);
    a1 = __builtin_amdgcn_mfma_f32_16x16x32_bf16(qf[1][1], kf1, a1, 0,0,0);

    int m = m0 + wave*16 + li;
    int xm = 0, ym = 0;
    bool mv = (m > 0 && m < SEQ);
    if (mv) { xm = (m-1) % 24; ym = (m-1) / 24; }
#pragma unroll
    for (int i = 0; i < 2; ++i) {
#pragma unroll
      for (int rg = 0; rg < 4; ++rg) {
        int nloc = i*16 + g*4 + rg;
        int n = r0 + nloc;
        float s = (i == 0) ? a0[rg] : a1[rg];
        int xi = 0, yi = 0;
        if (mv && n > 0) { xi = xm - xn[i][rg] + 25; yi = ym - yn[i][rg] + 25; }
        s = (s + bf2f(TB[nloc*100 + xi]) + bf2f(TB[nloc*100 + 50 + yi])) * 0.125f;
        sreg[i][kt][rg] = (m < SEQ) ? s : -INFINITY;
      }
    }
    __syncthreads();
  }

  // ---- Phase B: softmax (regs) -> Ps bf16; col/row sums + L ----
  float M[2][4];
#pragma unroll
  for (int i = 0; i < 2; ++i)
#pragma unroll
    for (int rg = 0; rg < 4; ++rg) {
      float mx = -INFINITY;
#pragma unroll
      for (int kt = 0; kt < 10; ++kt) mx = fmaxf(mx, sreg[i][kt][rg]);
      mx = fmaxf(mx, __shfl_xor(mx, 1));
      mx = fmaxf(mx, __shfl_xor(mx, 2));
      mx = fmaxf(mx, __shfl_xor(mx, 4));
      mx = fmaxf(mx, __shfl_xor(mx, 8));
      M[i][rg] = mx;
      if (li == 0) red[i*16 + g*4 + rg][wave] = mx;
    }
  __syncthreads();
#pragma unroll
  for (int i = 0; i < 2; ++i)
#pragma unroll
    for (int rg = 0; rg < 4; ++rg) {
      float4 r4 = *(float4*)&red[i*16 + g*4 + rg][0];
      M[i][rg] = fmaxf(fmaxf(r4.x, r4.y), fmaxf(r4.z, r4.w));
    }
  __syncthreads();   // all max reads done before red reuse

  float Lp[2][4];
#pragma unroll
  for (int i = 0; i < 2; ++i)
#pragma unroll
    for (int rg = 0; rg < 4; ++rg) Lp[i][rg] = 0.f;
#pragma unroll
  for (int kt = 0; kt < 10; ++kt) {
    int col = kt*64 + wave*16 + li;
#pragma unroll
    for (int i = 0; i < 2; ++i)
#pragma unroll
      for (int rg = 0; rg < 4; ++rg) {
        float p = __expf(sreg[i][kt][rg] - M[i][rg]);   // -inf -> 0
        Lp[i][rg] += p;
        if (col < SW) Ps[i*16 + g*4 + rg][col] = f2bf(p);
      }
  }
#pragma unroll
  for (int i = 0; i < 2; ++i)
#pragma unroll
    for (int rg = 0; rg < 4; ++rg) {
      float s = Lp[i][rg];
      s += __shfl_xor(s, 1); s += __shfl_xor(s, 2);
      s += __shfl_xor(s, 4); s += __shfl_xor(s, 8);
      if (li == 0) red[i*16 + g*4 + rg][wave] = s;
    }
  __syncthreads();   // Ps complete; red sums ready
  float* CS = (float*)TBCS;                            // [32][49]
  if (wave == 0 && li == 0) {
#pragma unroll
    for (int i = 0; i < 2; ++i)
#pragma unroll
      for (int rg = 0; rg < 4; ++rg) {
        int nloc = i*16 + g*4 + rg;
        float4 r4 = *(float4*)&red[nloc][0];
        CS[nloc*49 + 48] = r4.x + r4.y + r4.z + r4.w;
      }
  }
  for (int task = tid; task < TRB*48; task += 256) {
    int r = task / 48, k = task - (task/48)*48;
    float s = 0.f;
    if (k < 24) {
#pragma unroll
      for (int c2 = 0; c2 < 24; ++c2) s += bf2f(Ps[r][1 + c2*24 + k]);
    } else {
      int rw = k - 24;
#pragma unroll
      for (int c2 = 0; c2 < 24; ++c2) s += bf2f(Ps[r][1 + rw*24 + c2]);
    }
    CS[r*49 + k] = s;
  }

  // ---- Phase C: O = P.V via MFMA (V pre-transposed: vt[d][m]) ----
  f32x4 oa0 = {0.f,0.f,0.f,0.f}, oa1 = {0.f,0.f,0.f,0.f};
#pragma unroll
  for (int vt = 0; vt < 10; ++vt) {
    int m0 = vt*64;
    __syncthreads();   // previous KV reads (and CS/Ps writes on vt=0) done
    {  // stage Vt tile (64 d x 64 m)
      int d = tid >> 2, seg = tid & 3;
      uint4 v0 = {0,0,0,0}, v1 = {0,0,0,0};
      if (vt < 9) {
        const uint4* p = (const uint4*)&vtg[vtbase + (size_t)d*VTS + m0 + seg*16];
        v0 = p[0]; v1 = p[1];
      } else if (seg == 0) {
        ((unsigned short*)&v0)[0] = vtg[vtbase + (size_t)d*VTS + 576];
      }
      *(uint4*)&KV[d][seg*16]     = v0;
      *(uint4*)&KV[d][seg*16 + 8] = v1;
    }
    __syncthreads();
    s16x8 vf0 = *(const s16x8*)&KV[wave*16 + li][g*8];
    s16x8 vf1 = *(const s16x8*)&KV[wave*16 + li][32 + g*8];
    s16x8 af00, af01, af10, af11;
    if (vt < 9) {
      af00 = *(const s16x8*)&Ps[li][m0 + g*8];
      af01 = *(const s16x8*)&Ps[li][m0 + 32 + g*8];
      af10 = *(const s16x8*)&Ps[16 + li][m0 + g*8];
      af11 = *(const s16x8*)&Ps[16 + li][m0 + 32 + g*8];
    } else {
      af00 = (g == 0) ? *(const s16x8*)&Ps[li][576] : z8;
      af10 = (g == 0) ? *(const s16x8*)&Ps[16 + li][576] : z8;
      af01 = z8; af11 = z8;
    }
    oa0 = __builtin_amdgcn_mfma_f32_16x16x32_bf16(af00, vf0, oa0, 0,0,0);
    oa1 = __builtin_amdgcn_mfma_f32_16x16x32_bf16(af10, vf0, oa1, 0,0,0);
    oa0 = __builtin_amdgcn_mfma_f32_16x16x32_bf16(af01, vf1, oa0, 0,0,0);
    oa1 = __builtin_amdgcn_mfma_f32_16x16x32_bf16(af11, vf1, oa1, 0,0,0);
  }

  // ---- Epilogue: + v-bias, /L, write bf16 (B,N,H,D) ----
  {
    int d = wave*16 + li;
    const float* tab = (d < 32) ? vxe : vye;
    int dd = d & 31;
    bool useX = (d < 32);
    int bI = bh / NH, hI = bh - bI*NH;
#pragma unroll
    for (int i = 0; i < 2; ++i) {
#pragma unroll
      for (int rg = 0; rg < 4; ++rg) {
        int nloc = i*16 + g*4 + rg;
        int n = r0 + nloc;
        if (n >= SEQ) continue;
        float Lr = CS[nloc*49 + 48];
        float bias;
        if (n == 0) {
          bias = Lr * tab[dd];
        } else {
          int cn = useX ? ((n-1) % 24) : ((n-1) / 24);
          bias = bf2f(Ps[nloc][0]) * tab[dd];
#pragma unroll
          for (int c = 0; c < 24; ++c) {
            float w = CS[nloc*49 + (useX ? c : 24 + c)];
            bias = fmaf(w, tab[(c - cn + 25)*32 + dd], bias);
          }
        }
        float o = ((i == 0 ? oa0[rg] : oa1[rg]) + bias) / Lr;
        og[(((size_t)bI*SEQ + n)*NH + hI)*DH + d] = f2bf(o);
      }
    }
  }
}

// ---------------------------------------------------------------------------
// ws (ushorts): q 3.545M, k 3.545M, vt 3.637M, ows 3.545M, xbf 3.545M,
// wqkv 1.769M, wproj 0.590M  => 40.4 MB total (< 56.7 MB proven budget).
// ---------------------------------------------------------------------------
extern "C" void kernel_launch(void* const* d_in, const int* in_sizes, int n_in,
                              void* d_out, int out_size, void* d_ws, size_t ws_size,
                              hipStream_t stream)
{
  const float* x     = (const float*)d_in[0];
  const float* qkvw  = (const float*)d_in[1];
  const float* projw = (const float*)d_in[2];
  const float* qxe   = (const float*)d_in[3];
  const float* qye   = (const float*)d_in[4];
  const float* vxe   = (const float*)d_in[5];
  const float* vye   = (const float*)d_in[6];
  float* out = (float*)d_out;

  const size_t SLc = (size_t)BHC * SEQ * DH;        // 3,545,088
  const size_t VTL = (size_t)BHC * DH * VTS;        // 3,637,248
  unsigned short* qws   = (unsigned short*)d_ws;
  unsigned short* kws   = qws + SLc;
  unsigned short* vtws  = kws + SLc;
  unsigned short* ows   = vtws + VTL;
  unsigned short* xbf   = ows + SLc;
  unsigned short* wqkv  = xbf + SLc;
  unsigned short* wproj = wqkv + (size_t)3*EMB*EMB;

  cast_kernel<<<(3*EMB*EMB/4 + 255)/256, 256, 0, stream>>>(qkvw, wqkv, 3*EMB*EMB/4);
  cast_kernel<<<(EMB*EMB/4 + 255)/256, 256, 0, stream>>>(projw, wproj, EMB*EMB/4);

  dim3 g1(3*EMB/GT, (MC + GT - 1)/GT);   // 18 x 37
  dim3 g2((SEQ + TRB - 1)/TRB, BHC);     // 19 x 96
  dim3 g3(EMB/GT, (MC + GT - 1)/GT);     // 6 x 37

  for (int c = 0; c < NC; ++c) {
    const float* xc = x   + (size_t)c * MC * EMB;
    float*       oc = out + (size_t)c * MC * EMB;
    cast_kernel<<<(MC*EMB/4 + 255)/256, 256, 0, stream>>>(xc, xbf, MC*EMB/4);
    gemm_bf16<<<g1, 256, 0, stream>>>(xbf, wqkv, qws, kws, vtws, nullptr, MC, 3*EMB, 0);
    attn_kernel<<<g2, 256, 0, stream>>>(qws, kws, vtws, qxe, qye, vxe, vye, ows);
    gemm_bf16<<<g3, 256, 0, stream>>>(ows, wproj, nullptr, nullptr, nullptr, oc, MC, EMB, 1);
  }
}

// Round 6
// 576.552 us; speedup vs baseline: 2.9725x; 1.0730x over previous
//
#include <hip/hip_runtime.h>
#include <math.h>

#define SEQ 577
#define NH 12
#define DH 64
#define EMB 768
#define NBATCH 16
#define NC 2
#define BC (NBATCH/NC)
#define MC (BC*SEQ)      // 4616 rows per chunk
#define BHC (BC*NH)      // 96 (b,h) per chunk
#define VTS 592          // vt row stride in m (16 ushort aligned, >= 577)

typedef float f32x4 __attribute__((ext_vector_type(4)));
typedef short s16x8 __attribute__((ext_vector_type(8)));

__device__ __forceinline__ float bf2f(unsigned short u) {
  union { unsigned int i; float f; } c; c.i = ((unsigned int)u) << 16; return c.f;
}
__device__ __forceinline__ unsigned short f2bf(float f) {
  union { float f; unsigned int i; } c; c.f = f;
  unsigned int r = c.i + 0x7FFFu + ((c.i >> 16) & 1u);   // round-nearest-even
  return (unsigned short)(r >> 16);
}

// ---------------------------------------------------------------------------
__global__ __launch_bounds__(256) void cast_kernel(
    const float* __restrict__ s, unsigned short* __restrict__ d, int n4)
{
  int i = blockIdx.x * 256 + threadIdx.x;
  if (i < n4) {
    float4 v = *(const float4*)&s[(size_t)i*4];
    ushort4 o; o.x = f2bf(v.x); o.y = f2bf(v.y); o.z = f2bf(v.z); o.w = f2bf(v.w);
    *(ushort4*)&d[(size_t)i*4] = o;
  }
}

// ---------------------------------------------------------------------------
// bf16 MFMA GEMM (NT). mode 0: scatter into q/k (b,h,n,d) and V TRANSPOSED
// vt (b,h,d,m) with m-stride VTS. mode 1: fp32 row-major Cf.
// ---------------------------------------------------------------------------
#define GT 128
__global__ __launch_bounds__(256) void gemm_bf16(
    const unsigned short* __restrict__ A, const unsigned short* __restrict__ Bm,
    unsigned short* __restrict__ Cq, unsigned short* __restrict__ Ck,
    unsigned short* __restrict__ Cv, float* __restrict__ Cf,
    int M, int N, int mode)
{
  __shared__ __align__(16) unsigned short As[GT][40];
  __shared__ __align__(16) unsigned short Bs[GT][40];
  const int tid = threadIdx.x;
  const int wave = tid >> 6, lane = tid & 63;
  const int wr = wave >> 1, wc = wave & 1;
  const int li = lane & 15, g = lane >> 4;
  const int r0 = blockIdx.y * GT, c0 = blockIdx.x * GT;
  const int srow = tid >> 1, sseg = tid & 1;

  f32x4 acc[4][4];
#pragma unroll
  for (int i = 0; i < 4; ++i)
#pragma unroll
    for (int j = 0; j < 4; ++j) { acc[i][j][0]=0.f; acc[i][j][1]=0.f; acc[i][j][2]=0.f; acc[i][j][3]=0.f; }

  for (int k0 = 0; k0 < EMB; k0 += 32) {
    uint4 a0 = {0,0,0,0}, a1 = {0,0,0,0}, b0 = {0,0,0,0}, b1 = {0,0,0,0};
    int gr = r0 + srow;
    if (gr < M) {
      const uint4* p = (const uint4*)&A[(size_t)gr*EMB + k0 + sseg*16];
      a0 = p[0]; a1 = p[1];
    }
    int gc = c0 + srow;
    if (gc < N) {
      const uint4* p = (const uint4*)&Bm[(size_t)gc*EMB + k0 + sseg*16];
      b0 = p[0]; b1 = p[1];
    }
    *(uint4*)&As[srow][sseg*16]   = a0;
    *(uint4*)&As[srow][sseg*16+8] = a1;
    *(uint4*)&Bs[srow][sseg*16]   = b0;
    *(uint4*)&Bs[srow][sseg*16+8] = b1;
    __syncthreads();

    s16x8 af[4], bfv[4];
#pragma unroll
    for (int i = 0; i < 4; ++i) af[i]  = *(const s16x8*)&As[wr*64 + i*16 + li][g*8];
#pragma unroll
    for (int j = 0; j < 4; ++j) bfv[j] = *(const s16x8*)&Bs[wc*64 + j*16 + li][g*8];
#pragma unroll
    for (int i = 0; i < 4; ++i)
#pragma unroll
      for (int j = 0; j < 4; ++j)
        acc[i][j] = __builtin_amdgcn_mfma_f32_16x16x32_bf16(af[i], bfv[j], acc[i][j], 0, 0, 0);
    __syncthreads();
  }

#pragma unroll
  for (int i = 0; i < 4; ++i) {
    int rbase = r0 + wr*64 + i*16 + g*4;
#pragma unroll
    for (int j = 0; j < 4; ++j) {
      int col = c0 + wc*64 + j*16 + li;
#pragma unroll
      for (int rg = 0; rg < 4; ++rg) {
        int gr = rbase + rg;
        if (gr >= M) continue;
        float val = acc[i][j][rg];
        if (mode == 1) {
          Cf[(size_t)gr*N + col] = val;
        } else {
          int t  = col / EMB;
          int ct = col - t*EMB;
          int h  = ct >> 6, dd = ct & 63;
          int brow = gr / SEQ, nrow = gr - brow*SEQ;
          if (t == 0)
            Cq[(((size_t)brow*NH + h)*SEQ + nrow)*DH + dd] = f2bf(val);
          else if (t == 1)
            Ck[(((size_t)brow*NH + h)*SEQ + nrow)*DH + dd] = f2bf(val);
          else
            Cv[(((size_t)brow*NH + h)*DH + dd)*VTS + nrow] = f2bf(val);
        }
      }
    }
  }
}

// ---------------------------------------------------------------------------
// MFMA fused attention — round-4 structure (known good), with the private
// score ARRAY replaced by 20 NAMED f32x4 registers via macro expansion.
// (SROA cannot promote sreg[i][kt][rg] because kt is a loop variable of a
// barriered loop -> round 4 spilled 320 B/lane to scratch: 244 MB WRITE_SIZE.)
// Block = 32 q-rows of one (b,h); 4 waves.
// LDS: Ps 37376 + KV 9216 + TBCS 6400 + red 512 = 53504 B -> 3 blocks/CU.
// ---------------------------------------------------------------------------
#define TRB 32
#define SW 584

#define FOR_KT(X) X(0,s0a,s0b) X(1,s1a,s1b) X(2,s2a,s2b) X(3,s3a,s3b) \
                  X(4,s4a,s4b) X(5,s5a,s5b) X(6,s6a,s6b) X(7,s7a,s7b) \
                  X(8,s8a,s8b) X(9,s9a,s9b)

__global__ __launch_bounds__(256, 2) void attn_kernel(
    const unsigned short* __restrict__ qg, const unsigned short* __restrict__ kg,
    const unsigned short* __restrict__ vtg,
    const float* __restrict__ qxe, const float* __restrict__ qye,
    const float* __restrict__ vxe, const float* __restrict__ vye,
    unsigned short* __restrict__ og)
{
  __shared__ __align__(16) unsigned short Ps[TRB][SW];
  __shared__ __align__(16) unsigned short KV[64][72];
  __shared__ __align__(16) unsigned char  TBCS[TRB*200];
  __shared__ __align__(16) float red[TRB][4];

  const int tid  = threadIdx.x;
  const int wave = tid >> 6, lane = tid & 63;
  const int li = lane & 15, gg = lane >> 4;
  const int bh = blockIdx.y;
  const int r0 = blockIdx.x * TRB;
  const size_t qkbase = (size_t)bh * SEQ * DH;
  const size_t vtbase = (size_t)bh * DH * VTS;
  const s16x8 z8 = {0,0,0,0,0,0,0,0};

  // ---- Q A-frags from global (kept resident) ----
  s16x8 qf[2][2];
#pragma unroll
  for (int i = 0; i < 2; ++i) {
    int n = r0 + i*16 + li;
#pragma unroll
    for (int s = 0; s < 2; ++s)
      qf[i][s] = (n < SEQ) ? *(const s16x8*)&qg[qkbase + (size_t)n*DH + s*32 + gg*8] : z8;
  }

  // ---- bias dot tables via MFMA: qx_dot/qy_dot [32 rows][50 bins] bf16 ----
  unsigned short* TB = (unsigned short*)TBCS;          // row stride 100
  {
    int bin = wave*16 + li;
    s16x8 bx = z8, by = z8;
    if (bin < 50) {
      float4 x0 = *(const float4*)&qxe[bin*32 + gg*8];
      float4 x1 = *(const float4*)&qxe[bin*32 + gg*8 + 4];
      float4 y0 = *(const float4*)&qye[bin*32 + gg*8];
      float4 y1 = *(const float4*)&qye[bin*32 + gg*8 + 4];
      bx[0]=f2bf(x0.x); bx[1]=f2bf(x0.y); bx[2]=f2bf(x0.z); bx[3]=f2bf(x0.w);
      bx[4]=f2bf(x1.x); bx[5]=f2bf(x1.y); bx[6]=f2bf(x1.z); bx[7]=f2bf(x1.w);
      by[0]=f2bf(y0.x); by[1]=f2bf(y0.y); by[2]=f2bf(y0.z); by[3]=f2bf(y0.w);
      by[4]=f2bf(y1.x); by[5]=f2bf(y1.y); by[6]=f2bf(y1.z); by[7]=f2bf(y1.w);
    }
    f32x4 ax0={0.f,0.f,0.f,0.f}, ax1={0.f,0.f,0.f,0.f};
    f32x4 ay0={0.f,0.f,0.f,0.f}, ay1={0.f,0.f,0.f,0.f};
    ax0 = __builtin_amdgcn_mfma_f32_16x16x32_bf16(qf[0][0], bx, ax0, 0,0,0);
    ax1 = __builtin_amdgcn_mfma_f32_16x16x32_bf16(qf[1][0], bx, ax1, 0,0,0);
    ay0 = __builtin_amdgcn_mfma_f32_16x16x32_bf16(qf[0][1], by, ay0, 0,0,0);
    ay1 = __builtin_amdgcn_mfma_f32_16x16x32_bf16(qf[1][1], by, ay1, 0,0,0);
    if (bin < 50) {
#pragma unroll
      for (int rg = 0; rg < 4; ++rg) {
        TB[(gg*4+rg)*100      + bin] = f2bf(ax0[rg]);
        TB[(16+gg*4+rg)*100   + bin] = f2bf(ax1[rg]);
        TB[(gg*4+rg)*100 + 50 + bin] = f2bf(ay0[rg]);
        TB[(16+gg*4+rg)*100+50+ bin] = f2bf(ay1[rg]);
      }
    }
  }

  // row coords for bias (per i,rg)
  int xn[2][4], yn[2][4];
#pragma unroll
  for (int i = 0; i < 2; ++i)
#pragma unroll
    for (int rg = 0; rg < 4; ++rg) {
      int n = r0 + i*16 + gg*4 + rg;
      if (n > 0 && n <= SEQ) { xn[i][rg] = (n-1) % 24; yn[i][rg] = (n-1) / 24; }
      else { xn[i][rg] = 0; yn[i][rg] = 0; }
    }
  __syncthreads();   // tables visible

  // ---- Phase A: QK^T + bias -> named score registers (no array!) ----
#define DECLS(KT, SA, SB) f32x4 SA, SB;
  FOR_KT(DECLS)
#undef DECLS

#define KTSTEP(KT, SA, SB) do {                                               \
    const int m0_ = (KT)*64;                                                  \
    { int mm_ = m0_ + (tid >> 2), seg_ = tid & 3;                             \
      uint4 v0_ = {0,0,0,0}, v1_ = {0,0,0,0};                                 \
      if (mm_ < SEQ) {                                                        \
        const uint4* p_ = (const uint4*)&kg[qkbase + (size_t)mm_*DH + seg_*16];\
        v0_ = p_[0]; v1_ = p_[1];                                             \
      }                                                                       \
      *(uint4*)&KV[tid >> 2][seg_*16]     = v0_;                              \
      *(uint4*)&KV[tid >> 2][seg_*16 + 8] = v1_;                              \
    }                                                                         \
    __syncthreads();                                                          \
    { s16x8 kf0_ = *(const s16x8*)&KV[wave*16 + li][gg*8];                    \
      s16x8 kf1_ = *(const s16x8*)&KV[wave*16 + li][32 + gg*8];               \
      f32x4 a0_ = {0.f,0.f,0.f,0.f}, a1_ = {0.f,0.f,0.f,0.f};                 \
      a0_ = __builtin_amdgcn_mfma_f32_16x16x32_bf16(qf[0][0], kf0_, a0_, 0,0,0);\
      a1_ = __builtin_amdgcn_mfma_f32_16x16x32_bf16(qf[1][0], kf0_, a1_, 0,0,0);\
      a0_ = __builtin_amdgcn_mfma_f32_16x16x32_bf16(qf[0][1], kf1_, a0_, 0,0,0);\
      a1_ = __builtin_amdgcn_mfma_f32_16x16x32_bf16(qf[1][1], kf1_, a1_, 0,0,0);\
      int m_ = m0_ + wave*16 + li;                                            \
      int xm_ = 0, ym_ = 0;                                                   \
      bool mv_ = (m_ > 0 && m_ < SEQ);                                        \
      if (mv_) { xm_ = (m_-1) % 24; ym_ = (m_-1) / 24; }                      \
      _Pragma("unroll")                                                       \
      for (int rg = 0; rg < 4; ++rg) {                                        \
        { int nloc_ = gg*4 + rg; int n_ = r0 + nloc_;                         \
          float s_ = a0_[rg]; int xi_ = 0, yi_ = 0;                           \
          if (mv_ && n_ > 0) { xi_ = xm_ - xn[0][rg] + 25; yi_ = ym_ - yn[0][rg] + 25; } \
          s_ = (s_ + bf2f(TB[nloc_*100 + xi_]) + bf2f(TB[nloc_*100 + 50 + yi_])) * 0.125f; \
          SA[rg] = (m_ < SEQ) ? s_ : -INFINITY; }                             \
        { int nloc_ = 16 + gg*4 + rg; int n_ = r0 + nloc_;                    \
          float s_ = a1_[rg]; int xi_ = 0, yi_ = 0;                           \
          if (mv_ && n_ > 0) { xi_ = xm_ - xn[1][rg] + 25; yi_ = ym_ - yn[1][rg] + 25; } \
          s_ = (s_ + bf2f(TB[nloc_*100 + xi_]) + bf2f(TB[nloc_*100 + 50 + yi_])) * 0.125f; \
          SB[rg] = (m_ < SEQ) ? s_ : -INFINITY; }                             \
      }                                                                       \
    }                                                                         \
    __syncthreads();                                                          \
  } while (0);
  FOR_KT(KTSTEP)
#undef KTSTEP

  // ---- Phase B: softmax (named regs) -> Ps bf16; col/row sums + L ----
  f32x4 mxA = s0a, mxB = s0b;
#define MAXST(KT, SA, SB) if ((KT) > 0) {                                     \
    _Pragma("unroll")                                                         \
    for (int rg = 0; rg < 4; ++rg) {                                          \
      mxA[rg] = fmaxf(mxA[rg], SA[rg]);                                       \
      mxB[rg] = fmaxf(mxB[rg], SB[rg]);                                       \
    } }
  FOR_KT(MAXST)
#undef MAXST

  float MA[4], MB[4];
#pragma unroll
  for (int rg = 0; rg < 4; ++rg) {
    float mx = mxA[rg];
    mx = fmaxf(mx, __shfl_xor(mx, 1));
    mx = fmaxf(mx, __shfl_xor(mx, 2));
    mx = fmaxf(mx, __shfl_xor(mx, 4));
    mx = fmaxf(mx, __shfl_xor(mx, 8));
    if (li == 0) red[gg*4 + rg][wave] = mx;
    float mb = mxB[rg];
    mb = fmaxf(mb, __shfl_xor(mb, 1));
    mb = fmaxf(mb, __shfl_xor(mb, 2));
    mb = fmaxf(mb, __shfl_xor(mb, 4));
    mb = fmaxf(mb, __shfl_xor(mb, 8));
    if (li == 0) red[16 + gg*4 + rg][wave] = mb;
  }
  __syncthreads();
#pragma unroll
  for (int rg = 0; rg < 4; ++rg) {
    float4 ra = *(float4*)&red[gg*4 + rg][0];
    MA[rg] = fmaxf(fmaxf(ra.x, ra.y), fmaxf(ra.z, ra.w));
    float4 rb = *(float4*)&red[16 + gg*4 + rg][0];
    MB[rg] = fmaxf(fmaxf(rb.x, rb.y), fmaxf(rb.z, rb.w));
  }
  __syncthreads();   // all max reads done before red reuse

  f32x4 LpA = {0.f,0.f,0.f,0.f}, LpB = {0.f,0.f,0.f,0.f};
#define PROBST(KT, SA, SB) {                                                  \
    int col_ = (KT)*64 + wave*16 + li;                                        \
    _Pragma("unroll")                                                         \
    for (int rg = 0; rg < 4; ++rg) {                                          \
      float p_ = __expf(SA[rg] - MA[rg]);                                     \
      LpA[rg] += p_;                                                          \
      if (col_ < SW) Ps[gg*4 + rg][col_] = f2bf(p_);                          \
      float q_ = __expf(SB[rg] - MB[rg]);                                     \
      LpB[rg] += q_;                                                          \
      if (col_ < SW) Ps[16 + gg*4 + rg][col_] = f2bf(q_);                     \
    } }
  FOR_KT(PROBST)
#undef PROBST

#pragma unroll
  for (int rg = 0; rg < 4; ++rg) {
    float s = LpA[rg];
    s += __shfl_xor(s, 1); s += __shfl_xor(s, 2);
    s += __shfl_xor(s, 4); s += __shfl_xor(s, 8);
    if (li == 0) red[gg*4 + rg][wave] = s;
    float t = LpB[rg];
    t += __shfl_xor(t, 1); t += __shfl_xor(t, 2);
    t += __shfl_xor(t, 4); t += __shfl_xor(t, 8);
    if (li == 0) red[16 + gg*4 + rg][wave] = t;
  }
  __syncthreads();   // Ps complete; red sums ready
  float* CS = (float*)TBCS;                            // [32][49]; TB is dead
  if (wave == 0 && li == 0) {
#pragma unroll
    for (int i = 0; i < 2; ++i)
#pragma unroll
      for (int rg = 0; rg < 4; ++rg) {
        int nloc = i*16 + gg*4 + rg;
        float4 r4 = *(float4*)&red[nloc][0];
        CS[nloc*49 + 48] = r4.x + r4.y + r4.z + r4.w;
      }
  }
  for (int task = tid; task < TRB*48; task += 256) {
    int r = task / 48, k = task - (task/48)*48;
    float s = 0.f;
    if (k < 24) {
#pragma unroll
      for (int c2 = 0; c2 < 24; ++c2) s += bf2f(Ps[r][1 + c2*24 + k]);
    } else {
      int rw = k - 24;
#pragma unroll
      for (int c2 = 0; c2 < 24; ++c2) s += bf2f(Ps[r][1 + rw*24 + c2]);
    }
    CS[r*49 + k] = s;
  }

  // ---- Phase C: O = P.V via MFMA (V pre-transposed: vt[d][m]) ----
  f32x4 oa0 = {0.f,0.f,0.f,0.f}, oa1 = {0.f,0.f,0.f,0.f};
#pragma unroll
  for (int vt = 0; vt < 10; ++vt) {
    int m0 = vt*64;
    __syncthreads();   // prev KV reads done; vt=0: orders CS/Ps for reads below
    {  // stage Vt tile (64 d x 64 m)
      int d = tid >> 2, seg = tid & 3;
      uint4 v0 = {0,0,0,0}, v1 = {0,0,0,0};
      if (vt < 9) {
        const uint4* p = (const uint4*)&vtg[vtbase + (size_t)d*VTS + m0 + seg*16];
        v0 = p[0]; v1 = p[1];
      } else if (seg == 0) {
        ((unsigned short*)&v0)[0] = vtg[vtbase + (size_t)d*VTS + 576];
      }
      *(uint4*)&KV[d][seg*16]     = v0;
      *(uint4*)&KV[d][seg*16 + 8] = v1;
    }
    __syncthreads();
    s16x8 vf0 = *(const s16x8*)&KV[wave*16 + li][gg*8];
    s16x8 vf1 = *(const s16x8*)&KV[wave*16 + li][32 + gg*8];
    s16x8 af00, af01, af10, af11;
    if (vt < 9) {
      af00 = *(const s16x8*)&Ps[li][m0 + gg*8];
      af01 = *(const s16x8*)&Ps[li][m0 + 32 + gg*8];
      af10 = *(const s16x8*)&Ps[16 + li][m0 + gg*8];
      af11 = *(const s16x8*)&Ps[16 + li][m0 + 32 + gg*8];
    } else {
      af00 = (gg == 0) ? *(const s16x8*)&Ps[li][576] : z8;
      af10 = (gg == 0) ? *(const s16x8*)&Ps[16 + li][576] : z8;
      af01 = z8; af11 = z8;
    }
    oa0 = __builtin_amdgcn_mfma_f32_16x16x32_bf16(af00, vf0, oa0, 0,0,0);
    oa1 = __builtin_amdgcn_mfma_f32_16x16x32_bf16(af10, vf0, oa1, 0,0,0);
    oa0 = __builtin_amdgcn_mfma_f32_16x16x32_bf16(af01, vf1, oa0, 0,0,0);
    oa1 = __builtin_amdgcn_mfma_f32_16x16x32_bf16(af11, vf1, oa1, 0,0,0);
  }

  // ---- Epilogue: + v-bias, /L, write bf16 (B,N,H,D) ----
  {
    int d = wave*16 + li;
    const float* tab = (d < 32) ? vxe : vye;
    int dd = d & 31;
    bool useX = (d < 32);
    int bI = bh / NH, hI = bh - bI*NH;
#pragma unroll
    for (int i = 0; i < 2; ++i) {
#pragma unroll
      for (int rg = 0; rg < 4; ++rg) {
        int nloc = i*16 + gg*4 + rg;
        int n = r0 + nloc;
        if (n >= SEQ) continue;
        float Lr = CS[nloc*49 + 48];
        float bias;
        if (n == 0) {
          bias = Lr * tab[dd];
        } else {
          int cn = useX ? ((n-1) % 24) : ((n-1) / 24);
          bias = bf2f(Ps[nloc][0]) * tab[dd];
#pragma unroll
          for (int c = 0; c < 24; ++c) {
            float w = CS[nloc*49 + (useX ? c : 24 + c)];
            bias = fmaf(w, tab[(c - cn + 25)*32 + dd], bias);
          }
        }
        float o = ((i == 0 ? oa0[rg] : oa1[rg]) + bias) / Lr;
        og[(((size_t)bI*SEQ + n)*NH + hI)*DH + d] = f2bf(o);
      }
    }
  }
}

// ---------------------------------------------------------------------------
// ws (ushorts): q 3.545M, k 3.545M, vt 3.637M, ows 3.545M, xbf 3.545M,
// wqkv 1.769M, wproj 0.590M  => 40.35 MB total (< 56.7 MB proven budget).
// ---------------------------------------------------------------------------
extern "C" void kernel_launch(void* const* d_in, const int* in_sizes, int n_in,
                              void* d_out, int out_size, void* d_ws, size_t ws_size,
                              hipStream_t stream)
{
  const float* x     = (const float*)d_in[0];
  const float* qkvw  = (const float*)d_in[1];
  const float* projw = (const float*)d_in[2];
  const float* qxe   = (const float*)d_in[3];
  const float* qye   = (const float*)d_in[4];
  const float* vxe   = (const float*)d_in[5];
  const float* vye   = (const float*)d_in[6];
  float* out = (float*)d_out;

  const size_t SLc = (size_t)BHC * SEQ * DH;        // 3,545,088
  const size_t VTL = (size_t)BHC * DH * VTS;        // 3,637,248
  unsigned short* qws   = (unsigned short*)d_ws;
  unsigned short* kws   = qws + SLc;
  unsigned short* vtws  = kws + SLc;
  unsigned short* ows   = vtws + VTL;
  unsigned short* xbf   = ows + SLc;
  unsigned short* wqkv  = xbf + SLc;
  unsigned short* wproj = wqkv + (size_t)3*EMB*EMB;

  cast_kernel<<<(3*EMB*EMB/4 + 255)/256, 256, 0, stream>>>(qkvw, wqkv, 3*EMB*EMB/4);
  cast_kernel<<<(EMB*EMB/4 + 255)/256, 256, 0, stream>>>(projw, wproj, EMB*EMB/4);

  dim3 g1(3*EMB/GT, (MC + GT - 1)/GT);   // 18 x 37
  dim3 g2((SEQ + TRB - 1)/TRB, BHC);     // 19 x 96
  dim3 g3(EMB/GT, (MC + GT - 1)/GT);     // 6 x 37

  for (int c = 0; c < NC; ++c) {
    const float* xc = x   + (size_t)c * MC * EMB;
    float*       oc = out + (size_t)c * MC * EMB;
    cast_kernel<<<(MC*EMB/4 + 255)/256, 256, 0, stream>>>(xc, xbf, MC*EMB/4);
    gemm_bf16<<<g1, 256, 0, stream>>>(xbf, wqkv, qws, kws, vtws, nullptr, MC, 3*EMB, 0);
    attn_kernel<<<g2, 256, 0, stream>>>(qws, kws, vtws, qxe, qye, vxe, vye, ows);
    gemm_bf16<<<g3, 256, 0, stream>>>(ows, wproj, nullptr, nullptr, nullptr, oc, MC, EMB, 1);
  }
}

// Round 7
// 561.882 us; speedup vs baseline: 3.0501x; 1.0261x over previous
//
#include <hip/hip_runtime.h>
#include <math.h>

#define SEQ 577
#define NH 12
#define DH 64
#define EMB 768
#define NBATCH 16
#define NC 2
#define BC (NBATCH/NC)
#define MC (BC*SEQ)      // 4616 rows per chunk
#define BHC (BC*NH)      // 96 (b,h) per chunk
#define VTS 592          // vt row stride in m (16 ushort aligned, >= 577)

typedef float f32x4 __attribute__((ext_vector_type(4)));
typedef short s16x8 __attribute__((ext_vector_type(8)));

__device__ __forceinline__ float bf2f(unsigned short u) {
  union { unsigned int i; float f; } c; c.i = ((unsigned int)u) << 16; return c.f;
}
__device__ __forceinline__ unsigned short f2bf(float f) {
  union { float f; unsigned int i; } c; c.f = f;
  unsigned int r = c.i + 0x7FFFu + ((c.i >> 16) & 1u);   // round-nearest-even
  return (unsigned short)(r >> 16);
}

// ---------------------------------------------------------------------------
__global__ __launch_bounds__(256) void cast_kernel(
    const float* __restrict__ s, unsigned short* __restrict__ d, int n4)
{
  int i = blockIdx.x * 256 + threadIdx.x;
  if (i < n4) {
    float4 v = *(const float4*)&s[(size_t)i*4];
    ushort4 o; o.x = f2bf(v.x); o.y = f2bf(v.y); o.z = f2bf(v.z); o.w = f2bf(v.w);
    *(ushort4*)&d[(size_t)i*4] = o;
  }
}

// ---------------------------------------------------------------------------
// bf16 MFMA GEMM (NT). mode 0: scatter into q/k (b,h,n,d) and V TRANSPOSED
// vt (b,h,d,m) with m-stride VTS. mode 1: fp32 row-major Cf.
// ---------------------------------------------------------------------------
#define GT 128
__global__ __launch_bounds__(256) void gemm_bf16(
    const unsigned short* __restrict__ A, const unsigned short* __restrict__ Bm,
    unsigned short* __restrict__ Cq, unsigned short* __restrict__ Ck,
    unsigned short* __restrict__ Cv, float* __restrict__ Cf,
    int M, int N, int mode)
{
  __shared__ __align__(16) unsigned short As[GT][40];
  __shared__ __align__(16) unsigned short Bs[GT][40];
  const int tid = threadIdx.x;
  const int wave = tid >> 6, lane = tid & 63;
  const int wr = wave >> 1, wc = wave & 1;
  const int li = lane & 15, g = lane >> 4;
  const int r0 = blockIdx.y * GT, c0 = blockIdx.x * GT;
  const int srow = tid >> 1, sseg = tid & 1;

  f32x4 acc[4][4];
#pragma unroll
  for (int i = 0; i < 4; ++i)
#pragma unroll
    for (int j = 0; j < 4; ++j) { acc[i][j][0]=0.f; acc[i][j][1]=0.f; acc[i][j][2]=0.f; acc[i][j][3]=0.f; }

  for (int k0 = 0; k0 < EMB; k0 += 32) {
    uint4 a0 = {0,0,0,0}, a1 = {0,0,0,0}, b0 = {0,0,0,0}, b1 = {0,0,0,0};
    int gr = r0 + srow;
    if (gr < M) {
      const uint4* p = (const uint4*)&A[(size_t)gr*EMB + k0 + sseg*16];
      a0 = p[0]; a1 = p[1];
    }
    int gc = c0 + srow;
    if (gc < N) {
      const uint4* p = (const uint4*)&Bm[(size_t)gc*EMB + k0 + sseg*16];
      b0 = p[0]; b1 = p[1];
    }
    *(uint4*)&As[srow][sseg*16]   = a0;
    *(uint4*)&As[srow][sseg*16+8] = a1;
    *(uint4*)&Bs[srow][sseg*16]   = b0;
    *(uint4*)&Bs[srow][sseg*16+8] = b1;
    __syncthreads();

    s16x8 af[4], bfv[4];
#pragma unroll
    for (int i = 0; i < 4; ++i) af[i]  = *(const s16x8*)&As[wr*64 + i*16 + li][g*8];
#pragma unroll
    for (int j = 0; j < 4; ++j) bfv[j] = *(const s16x8*)&Bs[wc*64 + j*16 + li][g*8];
#pragma unroll
    for (int i = 0; i < 4; ++i)
#pragma unroll
      for (int j = 0; j < 4; ++j)
        acc[i][j] = __builtin_amdgcn_mfma_f32_16x16x32_bf16(af[i], bfv[j], acc[i][j], 0, 0, 0);
    __syncthreads();
  }

#pragma unroll
  for (int i = 0; i < 4; ++i) {
    int rbase = r0 + wr*64 + i*16 + g*4;
#pragma unroll
    for (int j = 0; j < 4; ++j) {
      int col = c0 + wc*64 + j*16 + li;
#pragma unroll
      for (int rg = 0; rg < 4; ++rg) {
        int gr = rbase + rg;
        if (gr >= M) continue;
        float val = acc[i][j][rg];
        if (mode == 1) {
          Cf[(size_t)gr*N + col] = val;
        } else {
          int t  = col / EMB;
          int ct = col - t*EMB;
          int h  = ct >> 6, dd = ct & 63;
          int brow = gr / SEQ, nrow = gr - brow*SEQ;
          if (t == 0)
            Cq[(((size_t)brow*NH + h)*SEQ + nrow)*DH + dd] = f2bf(val);
          else if (t == 1)
            Ck[(((size_t)brow*NH + h)*SEQ + nrow)*DH + dd] = f2bf(val);
          else
            Cv[(((size_t)brow*NH + h)*DH + dd)*VTS + nrow] = f2bf(val);
        }
      }
    }
  }
}

// ---------------------------------------------------------------------------
// MFMA fused attention — round-6 structure with the row dimension HALVED
// (TRB 32 -> 16): deletes the entire second row-group, cutting per-lane live
// registers from ~140 (80 score regs) to ~90 (40) -> no scratch spill
// (round 6: WRITE_SIZE 72.6 MB vs 7.1 MB output = residual spill traffic).
// Block = 16 q-rows of one (b,h); 4 waves; each wave owns a 16-m strip per
// 64-m tile. LDS: Ps 18688 + KV 9216 + TBCS 3200 + red 256 = 31360 B
// -> 5 blocks/CU.
// ---------------------------------------------------------------------------
#define TRB 16
#define SW 584

#define FOR_KT(X) X(0,s0) X(1,s1) X(2,s2) X(3,s3) X(4,s4) \
                  X(5,s5) X(6,s6) X(7,s7) X(8,s8) X(9,s9)

__global__ __launch_bounds__(256) void attn_kernel(
    const unsigned short* __restrict__ qg, const unsigned short* __restrict__ kg,
    const unsigned short* __restrict__ vtg,
    const float* __restrict__ qxe, const float* __restrict__ qye,
    const float* __restrict__ vxe, const float* __restrict__ vye,
    unsigned short* __restrict__ og)
{
  __shared__ __align__(16) unsigned short Ps[TRB][SW];
  __shared__ __align__(16) unsigned short KV[64][72];
  __shared__ __align__(16) unsigned char  TBCS[TRB*200];
  __shared__ __align__(16) float red[TRB][4];

  const int tid  = threadIdx.x;
  const int wave = tid >> 6, lane = tid & 63;
  const int li = lane & 15, gg = lane >> 4;
  const int bh = blockIdx.y;
  const int r0 = blockIdx.x * TRB;
  const size_t qkbase = (size_t)bh * SEQ * DH;
  const size_t vtbase = (size_t)bh * DH * VTS;
  const s16x8 z8 = {0,0,0,0,0,0,0,0};

  // ---- Q A-frags from global (kept resident through phase A) ----
  s16x8 qf0, qf1;
  {
    int n = r0 + li;
    qf0 = (n < SEQ) ? *(const s16x8*)&qg[qkbase + (size_t)n*DH + gg*8] : z8;
    qf1 = (n < SEQ) ? *(const s16x8*)&qg[qkbase + (size_t)n*DH + 32 + gg*8] : z8;
  }

  // ---- bias dot tables via MFMA: qx_dot/qy_dot [16 rows][50 bins] bf16 ----
  unsigned short* TB = (unsigned short*)TBCS;          // row stride 100
  {
    int bin = wave*16 + li;
    s16x8 bx = z8, by = z8;
    if (bin < 50) {
      float4 x0 = *(const float4*)&qxe[bin*32 + gg*8];
      float4 x1 = *(const float4*)&qxe[bin*32 + gg*8 + 4];
      float4 y0 = *(const float4*)&qye[bin*32 + gg*8];
      float4 y1 = *(const float4*)&qye[bin*32 + gg*8 + 4];
      bx[0]=f2bf(x0.x); bx[1]=f2bf(x0.y); bx[2]=f2bf(x0.z); bx[3]=f2bf(x0.w);
      bx[4]=f2bf(x1.x); bx[5]=f2bf(x1.y); bx[6]=f2bf(x1.z); bx[7]=f2bf(x1.w);
      by[0]=f2bf(y0.x); by[1]=f2bf(y0.y); by[2]=f2bf(y0.z); by[3]=f2bf(y0.w);
      by[4]=f2bf(y1.x); by[5]=f2bf(y1.y); by[6]=f2bf(y1.z); by[7]=f2bf(y1.w);
    }
    f32x4 ax0={0.f,0.f,0.f,0.f}, ay0={0.f,0.f,0.f,0.f};
    ax0 = __builtin_amdgcn_mfma_f32_16x16x32_bf16(qf0, bx, ax0, 0,0,0);
    ay0 = __builtin_amdgcn_mfma_f32_16x16x32_bf16(qf1, by, ay0, 0,0,0);
    if (bin < 50) {
#pragma unroll
      for (int rg = 0; rg < 4; ++rg) {
        TB[(gg*4+rg)*100      + bin] = f2bf(ax0[rg]);
        TB[(gg*4+rg)*100 + 50 + bin] = f2bf(ay0[rg]);
      }
    }
  }

  // row coords for bias (per rg)
  int xn[4], yn[4];
#pragma unroll
  for (int rg = 0; rg < 4; ++rg) {
    int n = r0 + gg*4 + rg;
    if (n > 0 && n <= SEQ) { xn[rg] = (n-1) % 24; yn[rg] = (n-1) / 24; }
    else { xn[rg] = 0; yn[rg] = 0; }
  }
  __syncthreads();   // tables visible

  // ---- Phase A: QK^T + bias -> named score registers (no array!) ----
#define DECLS(KT, SA) f32x4 SA;
  FOR_KT(DECLS)
#undef DECLS

#define KTSTEP(KT, SA) do {                                                   \
    const int m0_ = (KT)*64;                                                  \
    { int mm_ = m0_ + (tid >> 2), seg_ = tid & 3;                             \
      uint4 v0_ = {0,0,0,0}, v1_ = {0,0,0,0};                                 \
      if (mm_ < SEQ) {                                                        \
        const uint4* p_ = (const uint4*)&kg[qkbase + (size_t)mm_*DH + seg_*16];\
        v0_ = p_[0]; v1_ = p_[1];                                             \
      }                                                                       \
      *(uint4*)&KV[tid >> 2][seg_*16]     = v0_;                              \
      *(uint4*)&KV[tid >> 2][seg_*16 + 8] = v1_;                              \
    }                                                                         \
    __syncthreads();                                                          \
    { s16x8 kf0_ = *(const s16x8*)&KV[wave*16 + li][gg*8];                    \
      s16x8 kf1_ = *(const s16x8*)&KV[wave*16 + li][32 + gg*8];               \
      f32x4 a0_ = {0.f,0.f,0.f,0.f};                                          \
      a0_ = __builtin_amdgcn_mfma_f32_16x16x32_bf16(qf0, kf0_, a0_, 0,0,0);   \
      a0_ = __builtin_amdgcn_mfma_f32_16x16x32_bf16(qf1, kf1_, a0_, 0,0,0);   \
      int m_ = m0_ + wave*16 + li;                                            \
      int xm_ = 0, ym_ = 0;                                                   \
      bool mv_ = (m_ > 0 && m_ < SEQ);                                        \
      if (mv_) { xm_ = (m_-1) % 24; ym_ = (m_-1) / 24; }                      \
      _Pragma("unroll")                                                       \
      for (int rg = 0; rg < 4; ++rg) {                                        \
        int nloc_ = gg*4 + rg; int n_ = r0 + nloc_;                           \
        float s_ = a0_[rg]; int xi_ = 0, yi_ = 0;                             \
        if (mv_ && n_ > 0) { xi_ = xm_ - xn[rg] + 25; yi_ = ym_ - yn[rg] + 25; } \
        s_ = (s_ + bf2f(TB[nloc_*100 + xi_]) + bf2f(TB[nloc_*100 + 50 + yi_])) * 0.125f; \
        SA[rg] = (m_ < SEQ) ? s_ : -INFINITY;                                 \
      }                                                                       \
    }                                                                         \
    __syncthreads();                                                          \
  } while (0);
  FOR_KT(KTSTEP)
#undef KTSTEP

  // ---- Phase B: softmax (named regs) -> Ps bf16; col/row sums + L ----
  f32x4 mxA = s0;
#define MAXST(KT, SA) if ((KT) > 0) {                                         \
    _Pragma("unroll")                                                         \
    for (int rg = 0; rg < 4; ++rg) mxA[rg] = fmaxf(mxA[rg], SA[rg]); }
  FOR_KT(MAXST)
#undef MAXST

  float MA[4];
#pragma unroll
  for (int rg = 0; rg < 4; ++rg) {
    float mx = mxA[rg];
    mx = fmaxf(mx, __shfl_xor(mx, 1));
    mx = fmaxf(mx, __shfl_xor(mx, 2));
    mx = fmaxf(mx, __shfl_xor(mx, 4));
    mx = fmaxf(mx, __shfl_xor(mx, 8));
    if (li == 0) red[gg*4 + rg][wave] = mx;
  }
  __syncthreads();
#pragma unroll
  for (int rg = 0; rg < 4; ++rg) {
    float4 ra = *(float4*)&red[gg*4 + rg][0];
    MA[rg] = fmaxf(fmaxf(ra.x, ra.y), fmaxf(ra.z, ra.w));
  }
  __syncthreads();   // all max reads done before red reuse

  f32x4 LpA = {0.f,0.f,0.f,0.f};
#define PROBST(KT, SA) {                                                      \
    int col_ = (KT)*64 + wave*16 + li;                                        \
    _Pragma("unroll")                                                         \
    for (int rg = 0; rg < 4; ++rg) {                                          \
      float p_ = __expf(SA[rg] - MA[rg]);                                     \
      LpA[rg] += p_;                                                          \
      if (col_ < SW) Ps[gg*4 + rg][col_] = f2bf(p_);                          \
    } }
  FOR_KT(PROBST)
#undef PROBST

#pragma unroll
  for (int rg = 0; rg < 4; ++rg) {
    float s = LpA[rg];
    s += __shfl_xor(s, 1); s += __shfl_xor(s, 2);
    s += __shfl_xor(s, 4); s += __shfl_xor(s, 8);
    if (li == 0) red[gg*4 + rg][wave] = s;
  }
  __syncthreads();   // Ps complete; red sums ready
  float* CS = (float*)TBCS;                            // [16][49]; TB is dead
  if (wave == 0 && li == 0) {
#pragma unroll
    for (int rg = 0; rg < 4; ++rg) {
      int nloc = gg*4 + rg;
      float4 r4 = *(float4*)&red[nloc][0];
      CS[nloc*49 + 48] = r4.x + r4.y + r4.z + r4.w;
    }
  }
  for (int task = tid; task < TRB*48; task += 256) {
    int r = task / 48, k = task - (task/48)*48;
    float s = 0.f;
    if (k < 24) {
#pragma unroll
      for (int c2 = 0; c2 < 24; ++c2) s += bf2f(Ps[r][1 + c2*24 + k]);
    } else {
      int rw = k - 24;
#pragma unroll
      for (int c2 = 0; c2 < 24; ++c2) s += bf2f(Ps[r][1 + rw*24 + c2]);
    }
    CS[r*49 + k] = s;
  }

  // ---- Phase C: O = P.V via MFMA (V pre-transposed: vt[d][m]) ----
  f32x4 oa0 = {0.f,0.f,0.f,0.f};
#pragma unroll
  for (int vt = 0; vt < 10; ++vt) {
    int m0 = vt*64;
    __syncthreads();   // prev KV reads done; vt=0: orders CS/Ps writes
    {  // stage Vt tile (64 d x 64 m)
      int d = tid >> 2, seg = tid & 3;
      uint4 v0 = {0,0,0,0}, v1 = {0,0,0,0};
      if (vt < 9) {
        const uint4* p = (const uint4*)&vtg[vtbase + (size_t)d*VTS + m0 + seg*16];
        v0 = p[0]; v1 = p[1];
      } else if (seg == 0) {
        ((unsigned short*)&v0)[0] = vtg[vtbase + (size_t)d*VTS + 576];
      }
      *(uint4*)&KV[d][seg*16]     = v0;
      *(uint4*)&KV[d][seg*16 + 8] = v1;
    }
    __syncthreads();
    s16x8 vf0 = *(const s16x8*)&KV[wave*16 + li][gg*8];
    s16x8 vf1 = *(const s16x8*)&KV[wave*16 + li][32 + gg*8];
    s16x8 af00, af01;
    if (vt < 9) {
      af00 = *(const s16x8*)&Ps[li][m0 + gg*8];
      af01 = *(const s16x8*)&Ps[li][m0 + 32 + gg*8];
    } else {
      af00 = (gg == 0) ? *(const s16x8*)&Ps[li][576] : z8;
      af01 = z8;
    }
    oa0 = __builtin_amdgcn_mfma_f32_16x16x32_bf16(af00, vf0, oa0, 0,0,0);
    oa0 = __builtin_amdgcn_mfma_f32_16x16x32_bf16(af01, vf1, oa0, 0,0,0);
  }

  // ---- Epilogue: + v-bias, /L, write bf16 (B,N,H,D) ----
  {
    int d = wave*16 + li;
    const float* tab = (d < 32) ? vxe : vye;
    int dd = d & 31;
    bool useX = (d < 32);
    int bI = bh / NH, hI = bh - bI*NH;
#pragma unroll
    for (int rg = 0; rg < 4; ++rg) {
      int nloc = gg*4 + rg;
      int n = r0 + nloc;
      if (n >= SEQ) continue;
      float Lr = CS[nloc*49 + 48];
      float bias;
      if (n == 0) {
        bias = Lr * tab[dd];
      } else {
        int cn = useX ? ((n-1) % 24) : ((n-1) / 24);
        bias = bf2f(Ps[nloc][0]) * tab[dd];
#pragma unroll
        for (int c = 0; c < 24; ++c) {
          float w = CS[nloc*49 + (useX ? c : 24 + c)];
          bias = fmaf(w, tab[(c - cn + 25)*32 + dd], bias);
        }
      }
      float o = (oa0[rg] + bias) / Lr;
      og[(((size_t)bI*SEQ + n)*NH + hI)*DH + d] = f2bf(o);
    }
  }
}

// ---------------------------------------------------------------------------
// ws (ushorts): q 3.545M, k 3.545M, vt 3.637M, ows 3.545M, xbf 3.545M,
// wqkv 1.769M, wproj 0.590M  => 40.35 MB total (< 56.7 MB proven budget).
// ---------------------------------------------------------------------------
extern "C" void kernel_launch(void* const* d_in, const int* in_sizes, int n_in,
                              void* d_out, int out_size, void* d_ws, size_t ws_size,
                              hipStream_t stream)
{
  const float* x     = (const float*)d_in[0];
  const float* qkvw  = (const float*)d_in[1];
  const float* projw = (const float*)d_in[2];
  const float* qxe   = (const float*)d_in[3];
  const float* qye   = (const float*)d_in[4];
  const float* vxe   = (const float*)d_in[5];
  const float* vye   = (const float*)d_in[6];
  float* out = (float*)d_out;

  const size_t SLc = (size_t)BHC * SEQ * DH;        // 3,545,088
  const size_t VTL = (size_t)BHC * DH * VTS;        // 3,637,248
  unsigned short* qws   = (unsigned short*)d_ws;
  unsigned short* kws   = qws + SLc;
  unsigned short* vtws  = kws + SLc;
  unsigned short* ows   = vtws + VTL;
  unsigned short* xbf   = ows + SLc;
  unsigned short* wqkv  = xbf + SLc;
  unsigned short* wproj = wqkv + (size_t)3*EMB*EMB;

  cast_kernel<<<(3*EMB*EMB/4 + 255)/256, 256, 0, stream>>>(qkvw, wqkv, 3*EMB*EMB/4);
  cast_kernel<<<(EMB*EMB/4 + 255)/256, 256, 0, stream>>>(projw, wproj, EMB*EMB/4);

  dim3 g1(3*EMB/GT, (MC + GT - 1)/GT);   // 18 x 37
  dim3 g2((SEQ + TRB - 1)/TRB, BHC);     // 37 x 96
  dim3 g3(EMB/GT, (MC + GT - 1)/GT);     // 6 x 37

  for (int c = 0; c < NC; ++c) {
    const float* xc = x   + (size_t)c * MC * EMB;
    float*       oc = out + (size_t)c * MC * EMB;
    cast_kernel<<<(MC*EMB/4 + 255)/256, 256, 0, stream>>>(xc, xbf, MC*EMB/4);
    gemm_bf16<<<g1, 256, 0, stream>>>(xbf, wqkv, qws, kws, vtws, nullptr, MC, 3*EMB, 0);
    attn_kernel<<<g2, 256, 0, stream>>>(qws, kws, vtws, qxe, qye, vxe, vye, ows);
    gemm_bf16<<<g3, 256, 0, stream>>>(ows, wproj, nullptr, nullptr, nullptr, oc, MC, EMB, 1);
  }
}

// Round 8
// 477.499 us; speedup vs baseline: 3.5891x; 1.1767x over previous
//
#include <hip/hip_runtime.h>
#include <math.h>

#define SEQ 577
#define NH 12
#define DH 64
#define EMB 768
#define NBATCH 16
#define NC 2
#define BC (NBATCH/NC)
#define MC (BC*SEQ)      // 4616 rows per chunk
#define BHC (BC*NH)      // 96 (b,h) per chunk
#define VTS 592          // vt row stride in m (16 ushort aligned, >= 577)

typedef float f32x4 __attribute__((ext_vector_type(4)));
typedef short s16x8 __attribute__((ext_vector_type(8)));

__device__ __forceinline__ float bf2f(unsigned short u) {
  union { unsigned int i; float f; } c; c.i = ((unsigned int)u) << 16; return c.f;
}
__device__ __forceinline__ unsigned short f2bf(float f) {
  union { float f; unsigned int i; } c; c.f = f;
  unsigned int r = c.i + 0x7FFFu + ((c.i >> 16) & 1u);   // round-nearest-even
  return (unsigned short)(r >> 16);
}

// ---------------------------------------------------------------------------
__global__ __launch_bounds__(256) void cast_kernel(
    const float* __restrict__ s, unsigned short* __restrict__ d, int n4)
{
  int i = blockIdx.x * 256 + threadIdx.x;
  if (i < n4) {
    float4 v = *(const float4*)&s[(size_t)i*4];
    ushort4 o; o.x = f2bf(v.x); o.y = f2bf(v.y); o.z = f2bf(v.z); o.w = f2bf(v.w);
    *(ushort4*)&d[(size_t)i*4] = o;
  }
}

// ---------------------------------------------------------------------------
// bf16 MFMA GEMM (NT). mode 0: scatter into q/k (b,h,n,d) and V TRANSPOSED
// vt (b,h,d,m) with m-stride VTS. mode 1: fp32 row-major Cf.
// ---------------------------------------------------------------------------
#define GT 128
__global__ __launch_bounds__(256) void gemm_bf16(
    const unsigned short* __restrict__ A, const unsigned short* __restrict__ Bm,
    unsigned short* __restrict__ Cq, unsigned short* __restrict__ Ck,
    unsigned short* __restrict__ Cv, float* __restrict__ Cf,
    int M, int N, int mode)
{
  __shared__ __align__(16) unsigned short As[GT][40];
  __shared__ __align__(16) unsigned short Bs[GT][40];
  const int tid = threadIdx.x;
  const int wave = tid >> 6, lane = tid & 63;
  const int wr = wave >> 1, wc = wave & 1;
  const int li = lane & 15, g = lane >> 4;
  const int r0 = blockIdx.y * GT, c0 = blockIdx.x * GT;
  const int srow = tid >> 1, sseg = tid & 1;

  f32x4 acc[4][4];
#pragma unroll
  for (int i = 0; i < 4; ++i)
#pragma unroll
    for (int j = 0; j < 4; ++j) { acc[i][j][0]=0.f; acc[i][j][1]=0.f; acc[i][j][2]=0.f; acc[i][j][3]=0.f; }

  for (int k0 = 0; k0 < EMB; k0 += 32) {
    uint4 a0 = {0,0,0,0}, a1 = {0,0,0,0}, b0 = {0,0,0,0}, b1 = {0,0,0,0};
    int gr = r0 + srow;
    if (gr < M) {
      const uint4* p = (const uint4*)&A[(size_t)gr*EMB + k0 + sseg*16];
      a0 = p[0]; a1 = p[1];
    }
    int gc = c0 + srow;
    if (gc < N) {
      const uint4* p = (const uint4*)&Bm[(size_t)gc*EMB + k0 + sseg*16];
      b0 = p[0]; b1 = p[1];
    }
    *(uint4*)&As[srow][sseg*16]   = a0;
    *(uint4*)&As[srow][sseg*16+8] = a1;
    *(uint4*)&Bs[srow][sseg*16]   = b0;
    *(uint4*)&Bs[srow][sseg*16+8] = b1;
    __syncthreads();

    s16x8 af[4], bfv[4];
#pragma unroll
    for (int i = 0; i < 4; ++i) af[i]  = *(const s16x8*)&As[wr*64 + i*16 + li][g*8];
#pragma unroll
    for (int j = 0; j < 4; ++j) bfv[j] = *(const s16x8*)&Bs[wc*64 + j*16 + li][g*8];
#pragma unroll
    for (int i = 0; i < 4; ++i)
#pragma unroll
      for (int j = 0; j < 4; ++j)
        acc[i][j] = __builtin_amdgcn_mfma_f32_16x16x32_bf16(af[i], bfv[j], acc[i][j], 0, 0, 0);
    __syncthreads();
  }

#pragma unroll
  for (int i = 0; i < 4; ++i) {
    int rbase = r0 + wr*64 + i*16 + g*4;
#pragma unroll
    for (int j = 0; j < 4; ++j) {
      int col = c0 + wc*64 + j*16 + li;
#pragma unroll
      for (int rg = 0; rg < 4; ++rg) {
        int gr = rbase + rg;
        if (gr >= M) continue;
        float val = acc[i][j][rg];
        if (mode == 1) {
          Cf[(size_t)gr*N + col] = val;
        } else {
          int t  = col / EMB;
          int ct = col - t*EMB;
          int h  = ct >> 6, dd = ct & 63;
          int brow = gr / SEQ, nrow = gr - brow*SEQ;
          if (t == 0)
            Cq[(((size_t)brow*NH + h)*SEQ + nrow)*DH + dd] = f2bf(val);
          else if (t == 1)
            Ck[(((size_t)brow*NH + h)*SEQ + nrow)*DH + dd] = f2bf(val);
          else
            Cv[(((size_t)brow*NH + h)*DH + dd)*VTS + nrow] = f2bf(val);
        }
      }
    }
  }
}

// ---------------------------------------------------------------------------
// MFMA fused attention, round-7 math with LDS K/V staging DELETED:
// B-operand fragments for QK^T (K[m][d:16B]) and PV (Vt[d][m:16B]) are
// contiguous in global memory, so each wave MFMAs straight from global
// b128 loads. This removes 20 of ~25 __syncthreads per block (the
// barrier-drain that bounded round 7: all pipes <35% busy).
// Tail tiles read up to ~4KB past the k/vt sub-buffers: still inside d_ws,
// values discarded (scores -> -inf; V garbage x P=0; all ws patterns are
// finite bf16). Block = 16 q-rows; 4 waves; 5 barriers total.
// LDS: Ps 18688 + TBCS 3200 + red 256 = 22144 B.
// ---------------------------------------------------------------------------
#define TRB 16
#define SW 584

#define FOR_KT(X) X(0,s0) X(1,s1) X(2,s2) X(3,s3) X(4,s4) \
                  X(5,s5) X(6,s6) X(7,s7) X(8,s8) X(9,s9)

__global__ __launch_bounds__(256) void attn_kernel(
    const unsigned short* __restrict__ qg, const unsigned short* __restrict__ kg,
    const unsigned short* __restrict__ vtg,
    const float* __restrict__ qxe, const float* __restrict__ qye,
    const float* __restrict__ vxe, const float* __restrict__ vye,
    unsigned short* __restrict__ og)
{
  __shared__ __align__(16) unsigned short Ps[TRB][SW];
  __shared__ __align__(16) unsigned char  TBCS[TRB*200];
  __shared__ __align__(16) float red[TRB][4];

  const int tid  = threadIdx.x;
  const int wave = tid >> 6, lane = tid & 63;
  const int li = lane & 15, gg = lane >> 4;
  const int bh = blockIdx.y;
  const int r0 = blockIdx.x * TRB;
  const size_t qkbase = (size_t)bh * SEQ * DH;
  const size_t vtbase = (size_t)bh * DH * VTS;
  const s16x8 z8 = {0,0,0,0,0,0,0,0};

  // ---- Q A-frags from global (kept resident through phase A) ----
  s16x8 qf0, qf1;
  {
    int n = r0 + li;
    qf0 = (n < SEQ) ? *(const s16x8*)&qg[qkbase + (size_t)n*DH + gg*8] : z8;
    qf1 = (n < SEQ) ? *(const s16x8*)&qg[qkbase + (size_t)n*DH + 32 + gg*8] : z8;
  }

  // ---- bias dot tables via MFMA: qx_dot/qy_dot [16 rows][50 bins] bf16 ----
  unsigned short* TB = (unsigned short*)TBCS;          // row stride 100
  {
    int bin = wave*16 + li;
    s16x8 bx = z8, by = z8;
    if (bin < 50) {
      float4 x0 = *(const float4*)&qxe[bin*32 + gg*8];
      float4 x1 = *(const float4*)&qxe[bin*32 + gg*8 + 4];
      float4 y0 = *(const float4*)&qye[bin*32 + gg*8];
      float4 y1 = *(const float4*)&qye[bin*32 + gg*8 + 4];
      bx[0]=f2bf(x0.x); bx[1]=f2bf(x0.y); bx[2]=f2bf(x0.z); bx[3]=f2bf(x0.w);
      bx[4]=f2bf(x1.x); bx[5]=f2bf(x1.y); bx[6]=f2bf(x1.z); bx[7]=f2bf(x1.w);
      by[0]=f2bf(y0.x); by[1]=f2bf(y0.y); by[2]=f2bf(y0.z); by[3]=f2bf(y0.w);
      by[4]=f2bf(y1.x); by[5]=f2bf(y1.y); by[6]=f2bf(y1.z); by[7]=f2bf(y1.w);
    }
    f32x4 ax0={0.f,0.f,0.f,0.f}, ay0={0.f,0.f,0.f,0.f};
    ax0 = __builtin_amdgcn_mfma_f32_16x16x32_bf16(qf0, bx, ax0, 0,0,0);
    ay0 = __builtin_amdgcn_mfma_f32_16x16x32_bf16(qf1, by, ay0, 0,0,0);
    if (bin < 50) {
#pragma unroll
      for (int rg = 0; rg < 4; ++rg) {
        TB[(gg*4+rg)*100      + bin] = f2bf(ax0[rg]);
        TB[(gg*4+rg)*100 + 50 + bin] = f2bf(ay0[rg]);
      }
    }
  }

  // row coords for bias (per rg)
  int xn[4], yn[4];
#pragma unroll
  for (int rg = 0; rg < 4; ++rg) {
    int n = r0 + gg*4 + rg;
    if (n > 0 && n <= SEQ) { xn[rg] = (n-1) % 24; yn[rg] = (n-1) / 24; }
    else { xn[rg] = 0; yn[rg] = 0; }
  }
  __syncthreads();   // barrier 1: TB visible

  // ---- Phase A: QK^T + bias -> named score registers; NO barriers ----
  // K B-frag loaded straight from global: K[m][gg*8 +16B] is contiguous.
  const unsigned short* kwv = &kg[qkbase + (size_t)(wave*16 + li)*DH];
#define DECLS(KT, SA) f32x4 SA;
  FOR_KT(DECLS)
#undef DECLS

#define KTSTEP(KT, SA) do {                                                   \
    const int m0_ = (KT)*64;                                                  \
    s16x8 kf0_ = *(const s16x8*)&kwv[(size_t)m0_*DH + gg*8];                  \
    s16x8 kf1_ = *(const s16x8*)&kwv[(size_t)m0_*DH + 32 + gg*8];             \
    f32x4 a0_ = {0.f,0.f,0.f,0.f};                                           \
    a0_ = __builtin_amdgcn_mfma_f32_16x16x32_bf16(qf0, kf0_, a0_, 0,0,0);     \
    a0_ = __builtin_amdgcn_mfma_f32_16x16x32_bf16(qf1, kf1_, a0_, 0,0,0);     \
    int m_ = m0_ + wave*16 + li;                                              \
    int xm_ = 0, ym_ = 0;                                                     \
    bool mv_ = (m_ > 0 && m_ < SEQ);                                          \
    if (mv_) { xm_ = (m_-1) % 24; ym_ = (m_-1) / 24; }                        \
    _Pragma("unroll")                                                         \
    for (int rg = 0; rg < 4; ++rg) {                                          \
      int nloc_ = gg*4 + rg; int n_ = r0 + nloc_;                             \
      float s_ = a0_[rg]; int xi_ = 0, yi_ = 0;                               \
      if (mv_ && n_ > 0) { xi_ = xm_ - xn[rg] + 25; yi_ = ym_ - yn[rg] + 25; }\
      s_ = (s_ + bf2f(TB[nloc_*100 + xi_]) + bf2f(TB[nloc_*100 + 50 + yi_])) * 0.125f; \
      SA[rg] = (m_ < SEQ) ? s_ : -INFINITY;                                   \
    }                                                                         \
  } while (0);
  FOR_KT(KTSTEP)
#undef KTSTEP

  // ---- Phase B: softmax (named regs) -> Ps bf16; col/row sums + L ----
  f32x4 mxA = s0;
#define MAXST(KT, SA) if ((KT) > 0) {                                         \
    _Pragma("unroll")                                                         \
    for (int rg = 0; rg < 4; ++rg) mxA[rg] = fmaxf(mxA[rg], SA[rg]); }
  FOR_KT(MAXST)
#undef MAXST

  float MA[4];
#pragma unroll
  for (int rg = 0; rg < 4; ++rg) {
    float mx = mxA[rg];
    mx = fmaxf(mx, __shfl_xor(mx, 1));
    mx = fmaxf(mx, __shfl_xor(mx, 2));
    mx = fmaxf(mx, __shfl_xor(mx, 4));
    mx = fmaxf(mx, __shfl_xor(mx, 8));
    if (li == 0) red[gg*4 + rg][wave] = mx;
  }
  __syncthreads();   // barrier 2: per-wave maxes
#pragma unroll
  for (int rg = 0; rg < 4; ++rg) {
    float4 ra = *(float4*)&red[gg*4 + rg][0];
    MA[rg] = fmaxf(fmaxf(ra.x, ra.y), fmaxf(ra.z, ra.w));
  }
  __syncthreads();   // barrier 3: max reads done before red reuse

  f32x4 LpA = {0.f,0.f,0.f,0.f};
#define PROBST(KT, SA) {                                                      \
    int col_ = (KT)*64 + wave*16 + li;                                        \
    _Pragma("unroll")                                                         \
    for (int rg = 0; rg < 4; ++rg) {                                          \
      float p_ = __expf(SA[rg] - MA[rg]);                                     \
      LpA[rg] += p_;                                                          \
      if (col_ < SW) Ps[gg*4 + rg][col_] = f2bf(p_);                          \
    } }
  FOR_KT(PROBST)
#undef PROBST

#pragma unroll
  for (int rg = 0; rg < 4; ++rg) {
    float s = LpA[rg];
    s += __shfl_xor(s, 1); s += __shfl_xor(s, 2);
    s += __shfl_xor(s, 4); s += __shfl_xor(s, 8);
    if (li == 0) red[gg*4 + rg][wave] = s;
  }
  __syncthreads();   // barrier 4: Ps complete; red sums ready
  float* CS = (float*)TBCS;                            // [16][49]; TB is dead
  if (wave == 0 && li == 0) {
#pragma unroll
    for (int rg = 0; rg < 4; ++rg) {
      int nloc = gg*4 + rg;
      float4 r4 = *(float4*)&red[nloc][0];
      CS[nloc*49 + 48] = r4.x + r4.y + r4.z + r4.w;
    }
  }
  for (int task = tid; task < TRB*48; task += 256) {
    int r = task / 48, k = task - (task/48)*48;
    float s = 0.f;
    if (k < 24) {
#pragma unroll
      for (int c2 = 0; c2 < 24; ++c2) s += bf2f(Ps[r][1 + c2*24 + k]);
    } else {
      int rw = k - 24;
#pragma unroll
      for (int c2 = 0; c2 < 24; ++c2) s += bf2f(Ps[r][1 + rw*24 + c2]);
    }
    CS[r*49 + k] = s;
  }
  __syncthreads();   // barrier 5: CS complete (epilogue reads it)

  // ---- Phase C: O = P.V via MFMA straight from global Vt; NO barriers ----
  // Vt B-frag: Vt[d][m +16B] contiguous. d = wave*16 + li for this lane.
  const unsigned short* vwv = &vtg[vtbase + (size_t)(wave*16 + li)*VTS];
  f32x4 oa0 = {0.f,0.f,0.f,0.f};
#pragma unroll
  for (int vt = 0; vt < 10; ++vt) {
    int m0 = vt*64;
    s16x8 vf0 = *(const s16x8*)&vwv[m0 + gg*8];
    s16x8 vf1 = *(const s16x8*)&vwv[m0 + 32 + gg*8];
    s16x8 af00, af01;
    if (vt < 9) {
      af00 = *(const s16x8*)&Ps[li][m0 + gg*8];
      af01 = *(const s16x8*)&Ps[li][m0 + 32 + gg*8];
    } else {
      af00 = (gg == 0) ? *(const s16x8*)&Ps[li][576] : z8;   // probs 577..583 = 0
      af01 = z8;
    }
    oa0 = __builtin_amdgcn_mfma_f32_16x16x32_bf16(af00, vf0, oa0, 0,0,0);
    oa0 = __builtin_amdgcn_mfma_f32_16x16x32_bf16(af01, vf1, oa0, 0,0,0);
  }

  // ---- Epilogue: + v-bias, /L, write bf16 (B,N,H,D) ----
  {
    int d = wave*16 + li;
    const float* tab = (d < 32) ? vxe : vye;
    int dd = d & 31;
    bool useX = (d < 32);
    int bI = bh / NH, hI = bh - bI*NH;
#pragma unroll
    for (int rg = 0; rg < 4; ++rg) {
      int nloc = gg*4 + rg;
      int n = r0 + nloc;
      if (n >= SEQ) continue;
      float Lr = CS[nloc*49 + 48];
      float bias;
      if (n == 0) {
        bias = Lr * tab[dd];
      } else {
        int cn = useX ? ((n-1) % 24) : ((n-1) / 24);
        bias = bf2f(Ps[nloc][0]) * tab[dd];
#pragma unroll
        for (int c = 0; c < 24; ++c) {
          float w = CS[nloc*49 + (useX ? c : 24 + c)];
          bias = fmaf(w, tab[(c - cn + 25)*32 + dd], bias);
        }
      }
      float o = (oa0[rg] + bias) / Lr;
      og[(((size_t)bI*SEQ + n)*NH + hI)*DH + d] = f2bf(o);
    }
  }
}

// ---------------------------------------------------------------------------
// ws (ushorts): q 3.545M, k 3.545M, vt 3.637M, ows 3.545M, xbf 3.545M,
// wqkv 1.769M, wproj 0.590M  => 40.35 MB total (< 56.7 MB proven budget).
// ---------------------------------------------------------------------------
extern "C" void kernel_launch(void* const* d_in, const int* in_sizes, int n_in,
                              void* d_out, int out_size, void* d_ws, size_t ws_size,
                              hipStream_t stream)
{
  const float* x     = (const float*)d_in[0];
  const float* qkvw  = (const float*)d_in[1];
  const float* projw = (const float*)d_in[2];
  const float* qxe   = (const float*)d_in[3];
  const float* qye   = (const float*)d_in[4];
  const float* vxe   = (const float*)d_in[5];
  const float* vye   = (const float*)d_in[6];
  float* out = (float*)d_out;

  const size_t SLc = (size_t)BHC * SEQ * DH;        // 3,545,088
  const size_t VTL = (size_t)BHC * DH * VTS;        // 3,637,248
  unsigned short* qws   = (unsigned short*)d_ws;
  unsigned short* kws   = qws + SLc;
  unsigned short* vtws  = kws + SLc;
  unsigned short* ows   = vtws + VTL;
  unsigned short* xbf   = ows + SLc;
  unsigned short* wqkv  = xbf + SLc;
  unsigned short* wproj = wqkv + (size_t)3*EMB*EMB;

  cast_kernel<<<(3*EMB*EMB/4 + 255)/256, 256, 0, stream>>>(qkvw, wqkv, 3*EMB*EMB/4);
  cast_kernel<<<(EMB*EMB/4 + 255)/256, 256, 0, stream>>>(projw, wproj, EMB*EMB/4);

  dim3 g1(3*EMB/GT, (MC + GT - 1)/GT);   // 18 x 37
  dim3 g2((SEQ + TRB - 1)/TRB, BHC);     // 37 x 96
  dim3 g3(EMB/GT, (MC + GT - 1)/GT);     // 6 x 37

  for (int c = 0; c < NC; ++c) {
    const float* xc = x   + (size_t)c * MC * EMB;
    float*       oc = out + (size_t)c * MC * EMB;
    cast_kernel<<<(MC*EMB/4 + 255)/256, 256, 0, stream>>>(xc, xbf, MC*EMB/4);
    gemm_bf16<<<g1, 256, 0, stream>>>(xbf, wqkv, qws, kws, vtws, nullptr, MC, 3*EMB, 0);
    attn_kernel<<<g2, 256, 0, stream>>>(qws, kws, vtws, qxe, qye, vxe, vye, ows);
    gemm_bf16<<<g3, 256, 0, stream>>>(ows, wproj, nullptr, nullptr, nullptr, oc, MC, EMB, 1);
  }
}

// Round 9
// 451.258 us; speedup vs baseline: 3.7979x; 1.0582x over previous
//
#include <hip/hip_runtime.h>
#include <math.h>

#define SEQ 577
#define NH 12
#define DH 64
#define EMB 768
#define NBATCH 16
#define NC 2
#define BC (NBATCH/NC)
#define MC (BC*SEQ)      // 4616 rows per chunk
#define BHC (BC*NH)      // 96 (b,h) per chunk
#define VTS 592          // vt row stride in m (16 ushort aligned, >= 577)

typedef float f32x4 __attribute__((ext_vector_type(4)));
typedef short s16x8 __attribute__((ext_vector_type(8)));

__device__ __forceinline__ float bf2f(unsigned short u) {
  union { unsigned int i; float f; } c; c.i = ((unsigned int)u) << 16; return c.f;
}
__device__ __forceinline__ unsigned short f2bf(float f) {
  union { float f; unsigned int i; } c; c.f = f;
  unsigned int r = c.i + 0x7FFFu + ((c.i >> 16) & 1u);   // round-nearest-even
  return (unsigned short)(r >> 16);
}

// Async global->LDS, 16B per lane. LDS dest is wave-uniform base + lane*16.
__device__ __forceinline__ void gl_lds16(const unsigned short* g, unsigned short* l) {
  __builtin_amdgcn_global_load_lds(
      (const __attribute__((address_space(1))) unsigned int*)g,
      (__attribute__((address_space(3))) unsigned int*)l, 16, 0, 0);
}

// ---------------------------------------------------------------------------
__global__ __launch_bounds__(256) void cast_kernel(
    const float* __restrict__ s, unsigned short* __restrict__ d, int n4)
{
  int i = blockIdx.x * 256 + threadIdx.x;
  if (i < n4) {
    float4 v = *(const float4*)&s[(size_t)i*4];
    ushort4 o; o.x = f2bf(v.x); o.y = f2bf(v.y); o.z = f2bf(v.z); o.w = f2bf(v.w);
    *(ushort4*)&d[(size_t)i*4] = o;
  }
}

// ---------------------------------------------------------------------------
// bf16 MFMA GEMM (NT), m97-style global_load_lds staging (width=16).
// Tile [128][32] ushorts, no pad: 512 chunks of 16B; thread t stages chunks
// t and t+256 per operand; LDS base = &F[wave*512] (+2048) is wave-uniform,
// HW adds lane*16B. NO boundary predicates: OOB rows read later ws buffers
// (valid, finite bf16) and only feed C rows/cols that the epilogue masks.
// mode 0: scatter into q/k (b,h,n,d) and V TRANSPOSED vt (b,h,d,m) stride
// VTS. mode 1: fp32 row-major Cf.
// ---------------------------------------------------------------------------
#define GT 128
__global__ __launch_bounds__(256) void gemm_bf16(
    const unsigned short* __restrict__ A, const unsigned short* __restrict__ Bm,
    unsigned short* __restrict__ Cq, unsigned short* __restrict__ Ck,
    unsigned short* __restrict__ Cv, float* __restrict__ Cf,
    int M, int N, int mode)
{
  __shared__ __align__(16) unsigned short AsF[GT*32];
  __shared__ __align__(16) unsigned short BsF[GT*32];
  const int tid = threadIdx.x;
  const int wave = tid >> 6;
  const int lane = tid & 63;
  const int wr = wave >> 1, wc = wave & 1;
  const int li = lane & 15, g = lane >> 4;
  const int r0 = blockIdx.y * GT, c0 = blockIdx.x * GT;

  // chunk mapping: chunk c -> row c>>2, 8-ushort seg c&3; LDS ushort off c*8
  const int row1 = tid >> 2,          seg1 = tid & 3;
  const int row2 = (tid + 256) >> 2,  seg2 = tid & 3;   // (tid+256)&3 == tid&3
  const unsigned short* ga1 = &A [(size_t)(r0 + row1)*EMB + seg1*8];
  const unsigned short* ga2 = &A [(size_t)(r0 + row2)*EMB + seg2*8];
  const unsigned short* gb1 = &Bm[(size_t)(c0 + row1)*EMB + seg1*8];
  const unsigned short* gb2 = &Bm[(size_t)(c0 + row2)*EMB + seg2*8];
  unsigned short* la1 = &AsF[wave*512];
  unsigned short* la2 = &AsF[2048 + wave*512];
  unsigned short* lb1 = &BsF[wave*512];
  unsigned short* lb2 = &BsF[2048 + wave*512];

  f32x4 acc[4][4];
#pragma unroll
  for (int i = 0; i < 4; ++i)
#pragma unroll
    for (int j = 0; j < 4; ++j) { acc[i][j][0]=0.f; acc[i][j][1]=0.f; acc[i][j][2]=0.f; acc[i][j][3]=0.f; }

  for (int k0 = 0; k0 < EMB; k0 += 32) {
    gl_lds16(ga1 + k0, la1);
    gl_lds16(ga2 + k0, la2);
    gl_lds16(gb1 + k0, lb1);
    gl_lds16(gb2 + k0, lb2);
    __syncthreads();   // drains vmcnt incl. global_load_lds

    s16x8 af[4], bfv[4];
#pragma unroll
    for (int i = 0; i < 4; ++i) af[i]  = *(const s16x8*)&AsF[(wr*64 + i*16 + li)*32 + g*8];
#pragma unroll
    for (int j = 0; j < 4; ++j) bfv[j] = *(const s16x8*)&BsF[(wc*64 + j*16 + li)*32 + g*8];
#pragma unroll
    for (int i = 0; i < 4; ++i)
#pragma unroll
      for (int j = 0; j < 4; ++j)
        acc[i][j] = __builtin_amdgcn_mfma_f32_16x16x32_bf16(af[i], bfv[j], acc[i][j], 0, 0, 0);
    __syncthreads();
  }

#pragma unroll
  for (int i = 0; i < 4; ++i) {
    int rbase = r0 + wr*64 + i*16 + g*4;
#pragma unroll
    for (int j = 0; j < 4; ++j) {
      int col = c0 + wc*64 + j*16 + li;
#pragma unroll
      for (int rg = 0; rg < 4; ++rg) {
        int gr = rbase + rg;
        if (gr >= M) continue;
        float val = acc[i][j][rg];
        if (mode == 1) {
          Cf[(size_t)gr*N + col] = val;
        } else {
          int t  = col / EMB;
          int ct = col - t*EMB;
          int h  = ct >> 6, dd = ct & 63;
          int brow = gr / SEQ, nrow = gr - brow*SEQ;
          if (t == 0)
            Cq[(((size_t)brow*NH + h)*SEQ + nrow)*DH + dd] = f2bf(val);
          else if (t == 1)
            Ck[(((size_t)brow*NH + h)*SEQ + nrow)*DH + dd] = f2bf(val);
          else
            Cv[(((size_t)brow*NH + h)*DH + dd)*VTS + nrow] = f2bf(val);
        }
      }
    }
  }
}

// ---------------------------------------------------------------------------
// MFMA fused attention (round-8 structure) + v-bias tables staged in LDS:
// round 8's epilogue issued ~96 global float gathers per lane (24-iter loop
// x 4 rows) — a latency chain at 1.7 waves/SIMD. VXL/VYL (12.8 KB) kill it.
// Block = 16 q-rows; 4 waves; 5 barriers; K/V MFMA B-frags read straight
// from global (contiguous 16B). LDS: Ps 18688 + TBCS 3200 + red 256 +
// VXL/VYL 12800 = 34944 B -> 4 blocks/CU.
// ---------------------------------------------------------------------------
#define TRB 16
#define SW 584

#define FOR_KT(X) X(0,s0) X(1,s1) X(2,s2) X(3,s3) X(4,s4) \
                  X(5,s5) X(6,s6) X(7,s7) X(8,s8) X(9,s9)

__global__ __launch_bounds__(256) void attn_kernel(
    const unsigned short* __restrict__ qg, const unsigned short* __restrict__ kg,
    const unsigned short* __restrict__ vtg,
    const float* __restrict__ qxe, const float* __restrict__ qye,
    const float* __restrict__ vxe, const float* __restrict__ vye,
    unsigned short* __restrict__ og)
{
  __shared__ __align__(16) unsigned short Ps[TRB][SW];
  __shared__ __align__(16) unsigned char  TBCS[TRB*200];
  __shared__ __align__(16) float red[TRB][4];
  __shared__ __align__(16) float VXL[50*32];
  __shared__ __align__(16) float VYL[50*32];

  const int tid  = threadIdx.x;
  const int wave = tid >> 6, lane = tid & 63;
  const int li = lane & 15, gg = lane >> 4;
  const int bh = blockIdx.y;
  const int r0 = blockIdx.x * TRB;
  const size_t qkbase = (size_t)bh * SEQ * DH;
  const size_t vtbase = (size_t)bh * DH * VTS;
  const s16x8 z8 = {0,0,0,0,0,0,0,0};

  // ---- stage v-bias tables into LDS (1600 floats each) ----
  for (int t4 = tid; t4 < 400; t4 += 256) {
    ((float4*)VXL)[t4] = ((const float4*)vxe)[t4];
    ((float4*)VYL)[t4] = ((const float4*)vye)[t4];
  }

  // ---- Q A-frags from global (kept resident through phase A) ----
  s16x8 qf0, qf1;
  {
    int n = r0 + li;
    qf0 = (n < SEQ) ? *(const s16x8*)&qg[qkbase + (size_t)n*DH + gg*8] : z8;
    qf1 = (n < SEQ) ? *(const s16x8*)&qg[qkbase + (size_t)n*DH + 32 + gg*8] : z8;
  }

  // ---- bias dot tables via MFMA: qx_dot/qy_dot [16 rows][50 bins] bf16 ----
  unsigned short* TB = (unsigned short*)TBCS;          // row stride 100
  {
    int bin = wave*16 + li;
    s16x8 bx = z8, by = z8;
    if (bin < 50) {
      float4 x0 = *(const float4*)&qxe[bin*32 + gg*8];
      float4 x1 = *(const float4*)&qxe[bin*32 + gg*8 + 4];
      float4 y0 = *(const float4*)&qye[bin*32 + gg*8];
      float4 y1 = *(const float4*)&qye[bin*32 + gg*8 + 4];
      bx[0]=f2bf(x0.x); bx[1]=f2bf(x0.y); bx[2]=f2bf(x0.z); bx[3]=f2bf(x0.w);
      bx[4]=f2bf(x1.x); bx[5]=f2bf(x1.y); bx[6]=f2bf(x1.z); bx[7]=f2bf(x1.w);
      by[0]=f2bf(y0.x); by[1]=f2bf(y0.y); by[2]=f2bf(y0.z); by[3]=f2bf(y0.w);
      by[4]=f2bf(y1.x); by[5]=f2bf(y1.y); by[6]=f2bf(y1.z); by[7]=f2bf(y1.w);
    }
    f32x4 ax0={0.f,0.f,0.f,0.f}, ay0={0.f,0.f,0.f,0.f};
    ax0 = __builtin_amdgcn_mfma_f32_16x16x32_bf16(qf0, bx, ax0, 0,0,0);
    ay0 = __builtin_amdgcn_mfma_f32_16x16x32_bf16(qf1, by, ay0, 0,0,0);
    if (bin < 50) {
#pragma unroll
      for (int rg = 0; rg < 4; ++rg) {
        TB[(gg*4+rg)*100      + bin] = f2bf(ax0[rg]);
        TB[(gg*4+rg)*100 + 50 + bin] = f2bf(ay0[rg]);
      }
    }
  }

  // row coords for bias (per rg)
  int xn[4], yn[4];
#pragma unroll
  for (int rg = 0; rg < 4; ++rg) {
    int n = r0 + gg*4 + rg;
    if (n > 0 && n <= SEQ) { xn[rg] = (n-1) % 24; yn[rg] = (n-1) / 24; }
    else { xn[rg] = 0; yn[rg] = 0; }
  }
  __syncthreads();   // barrier 1: TB + VXL/VYL visible

  // ---- Phase A: QK^T + bias -> named score registers; NO barriers ----
  const unsigned short* kwv = &kg[qkbase + (size_t)(wave*16 + li)*DH];
#define DECLS(KT, SA) f32x4 SA;
  FOR_KT(DECLS)
#undef DECLS

#define KTSTEP(KT, SA) do {                                                   \
    const int m0_ = (KT)*64;                                                  \
    s16x8 kf0_ = *(const s16x8*)&kwv[(size_t)m0_*DH + gg*8];                  \
    s16x8 kf1_ = *(const s16x8*)&kwv[(size_t)m0_*DH + 32 + gg*8];             \
    f32x4 a0_ = {0.f,0.f,0.f,0.f};                                           \
    a0_ = __builtin_amdgcn_mfma_f32_16x16x32_bf16(qf0, kf0_, a0_, 0,0,0);     \
    a0_ = __builtin_amdgcn_mfma_f32_16x16x32_bf16(qf1, kf1_, a0_, 0,0,0);     \
    int m_ = m0_ + wave*16 + li;                                              \
    int xm_ = 0, ym_ = 0;                                                     \
    bool mv_ = (m_ > 0 && m_ < SEQ);                                          \
    if (mv_) { xm_ = (m_-1) % 24; ym_ = (m_-1) / 24; }                        \
    _Pragma("unroll")                                                         \
    for (int rg = 0; rg < 4; ++rg) {                                          \
      int nloc_ = gg*4 + rg; int n_ = r0 + nloc_;                             \
      float s_ = a0_[rg]; int xi_ = 0, yi_ = 0;                               \
      if (mv_ && n_ > 0) { xi_ = xm_ - xn[rg] + 25; yi_ = ym_ - yn[rg] + 25; }\
      s_ = (s_ + bf2f(TB[nloc_*100 + xi_]) + bf2f(TB[nloc_*100 + 50 + yi_])) * 0.125f; \
      SA[rg] = (m_ < SEQ) ? s_ : -INFINITY;                                   \
    }                                                                         \
  } while (0);
  FOR_KT(KTSTEP)
#undef KTSTEP

  // ---- Phase B: softmax (named regs) -> Ps bf16; col/row sums + L ----
  f32x4 mxA = s0;
#define MAXST(KT, SA) if ((KT) > 0) {                                         \
    _Pragma("unroll")                                                         \
    for (int rg = 0; rg < 4; ++rg) mxA[rg] = fmaxf(mxA[rg], SA[rg]); }
  FOR_KT(MAXST)
#undef MAXST

  float MA[4];
#pragma unroll
  for (int rg = 0; rg < 4; ++rg) {
    float mx = mxA[rg];
    mx = fmaxf(mx, __shfl_xor(mx, 1));
    mx = fmaxf(mx, __shfl_xor(mx, 2));
    mx = fmaxf(mx, __shfl_xor(mx, 4));
    mx = fmaxf(mx, __shfl_xor(mx, 8));
    if (li == 0) red[gg*4 + rg][wave] = mx;
  }
  __syncthreads();   // barrier 2: per-wave maxes
#pragma unroll
  for (int rg = 0; rg < 4; ++rg) {
    float4 ra = *(float4*)&red[gg*4 + rg][0];
    MA[rg] = fmaxf(fmaxf(ra.x, ra.y), fmaxf(ra.z, ra.w));
  }
  __syncthreads();   // barrier 3: max reads done before red reuse

  f32x4 LpA = {0.f,0.f,0.f,0.f};
#define PROBST(KT, SA) {                                                      \
    int col_ = (KT)*64 + wave*16 + li;                                        \
    _Pragma("unroll")                                                         \
    for (int rg = 0; rg < 4; ++rg) {                                          \
      float p_ = __expf(SA[rg] - MA[rg]);                                     \
      LpA[rg] += p_;                                                          \
      if (col_ < SW) Ps[gg*4 + rg][col_] = f2bf(p_);                          \
    } }
  FOR_KT(PROBST)
#undef PROBST

#pragma unroll
  for (int rg = 0; rg < 4; ++rg) {
    float s = LpA[rg];
    s += __shfl_xor(s, 1); s += __shfl_xor(s, 2);
    s += __shfl_xor(s, 4); s += __shfl_xor(s, 8);
    if (li == 0) red[gg*4 + rg][wave] = s;
  }
  __syncthreads();   // barrier 4: Ps complete; red sums ready
  float* CS = (float*)TBCS;                            // [16][49]; TB is dead
  if (wave == 0 && li == 0) {
#pragma unroll
    for (int rg = 0; rg < 4; ++rg) {
      int nloc = gg*4 + rg;
      float4 r4 = *(float4*)&red[nloc][0];
      CS[nloc*49 + 48] = r4.x + r4.y + r4.z + r4.w;
    }
  }
  for (int task = tid; task < TRB*48; task += 256) {
    int r = task / 48, k = task - (task/48)*48;
    float s = 0.f;
    if (k < 24) {
#pragma unroll
      for (int c2 = 0; c2 < 24; ++c2) s += bf2f(Ps[r][1 + c2*24 + k]);
    } else {
      int rw = k - 24;
#pragma unroll
      for (int c2 = 0; c2 < 24; ++c2) s += bf2f(Ps[r][1 + rw*24 + c2]);
    }
    CS[r*49 + k] = s;
  }
  __syncthreads();   // barrier 5: CS complete (epilogue reads it)

  // ---- Phase C: O = P.V via MFMA straight from global Vt; NO barriers ----
  const unsigned short* vwv = &vtg[vtbase + (size_t)(wave*16 + li)*VTS];
  f32x4 oa0 = {0.f,0.f,0.f,0.f};
#pragma unroll
  for (int vt = 0; vt < 10; ++vt) {
    int m0 = vt*64;
    s16x8 vf0 = *(const s16x8*)&vwv[m0 + gg*8];
    s16x8 vf1 = *(const s16x8*)&vwv[m0 + 32 + gg*8];
    s16x8 af00, af01;
    if (vt < 9) {
      af00 = *(const s16x8*)&Ps[li][m0 + gg*8];
      af01 = *(const s16x8*)&Ps[li][m0 + 32 + gg*8];
    } else {
      af00 = (gg == 0) ? *(const s16x8*)&Ps[li][576] : z8;   // probs 577..583 = 0
      af01 = z8;
    }
    oa0 = __builtin_amdgcn_mfma_f32_16x16x32_bf16(af00, vf0, oa0, 0,0,0);
    oa0 = __builtin_amdgcn_mfma_f32_16x16x32_bf16(af01, vf1, oa0, 0,0,0);
  }

  // ---- Epilogue: + v-bias (from LDS tables), /L, write bf16 (B,N,H,D) ----
  {
    int d = wave*16 + li;
    const float* tabL = (d < 32) ? VXL : VYL;
    int dd = d & 31;
    bool useX = (d < 32);
    int bI = bh / NH, hI = bh - bI*NH;
#pragma unroll
    for (int rg = 0; rg < 4; ++rg) {
      int nloc = gg*4 + rg;
      int n = r0 + nloc;
      if (n >= SEQ) continue;
      float Lr = CS[nloc*49 + 48];
      float bias;
      if (n == 0) {
        bias = Lr * tabL[dd];
      } else {
        int cn = useX ? ((n-1) % 24) : ((n-1) / 24);
        bias = bf2f(Ps[nloc][0]) * tabL[dd];
#pragma unroll
        for (int c = 0; c < 24; ++c) {
          float w = CS[nloc*49 + (useX ? c : 24 + c)];
          bias = fmaf(w, tabL[(c - cn + 25)*32 + dd], bias);
        }
      }
      float o = (oa0[rg] + bias) / Lr;
      og[(((size_t)bI*SEQ + n)*NH + hI)*DH + d] = f2bf(o);
    }
  }
}

// ---------------------------------------------------------------------------
// ws (ushorts): q 3.545M, k 3.545M, vt 3.637M, ows 3.545M, xbf 3.545M,
// wqkv 1.769M, wproj 0.590M  => 40.35 MB total (< 56.7 MB proven budget).
// ---------------------------------------------------------------------------
extern "C" void kernel_launch(void* const* d_in, const int* in_sizes, int n_in,
                              void* d_out, int out_size, void* d_ws, size_t ws_size,
                              hipStream_t stream)
{
  const float* x     = (const float*)d_in[0];
  const float* qkvw  = (const float*)d_in[1];
  const float* projw = (const float*)d_in[2];
  const float* qxe   = (const float*)d_in[3];
  const float* qye   = (const float*)d_in[4];
  const float* vxe   = (const float*)d_in[5];
  const float* vye   = (const float*)d_in[6];
  float* out = (float*)d_out;

  const size_t SLc = (size_t)BHC * SEQ * DH;        // 3,545,088
  const size_t VTL = (size_t)BHC * DH * VTS;        // 3,637,248
  unsigned short* qws   = (unsigned short*)d_ws;
  unsigned short* kws   = qws + SLc;
  unsigned short* vtws  = kws + SLc;
  unsigned short* ows   = vtws + VTL;
  unsigned short* xbf   = ows + SLc;
  unsigned short* wqkv  = xbf + SLc;
  unsigned short* wproj = wqkv + (size_t)3*EMB*EMB;

  cast_kernel<<<(3*EMB*EMB/4 + 255)/256, 256, 0, stream>>>(qkvw, wqkv, 3*EMB*EMB/4);
  cast_kernel<<<(EMB*EMB/4 + 255)/256, 256, 0, stream>>>(projw, wproj, EMB*EMB/4);

  dim3 g1(3*EMB/GT, (MC + GT - 1)/GT);   // 18 x 37
  dim3 g2((SEQ + TRB - 1)/TRB, BHC);     // 37 x 96
  dim3 g3(EMB/GT, (MC + GT - 1)/GT);     // 6 x 37

  for (int c = 0; c < NC; ++c) {
    const float* xc = x   + (size_t)c * MC * EMB;
    float*       oc = out + (size_t)c * MC * EMB;
    cast_kernel<<<(MC*EMB/4 + 255)/256, 256, 0, stream>>>(xc, xbf, MC*EMB/4);
    gemm_bf16<<<g1, 256, 0, stream>>>(xbf, wqkv, qws, kws, vtws, nullptr, MC, 3*EMB, 0);
    attn_kernel<<<g2, 256, 0, stream>>>(qws, kws, vtws, qxe, qye, vxe, vye, ows);
    gemm_bf16<<<g3, 256, 0, stream>>>(ows, wproj, nullptr, nullptr, nullptr, oc, MC, EMB, 1);
  }
}